// Round 3
// baseline (531.322 us; speedup 1.0000x reference)
//
#include <hip/hip_runtime.h>
#include <hip/hip_bf16.h>
#include <hip/hip_fp16.h>

#define NEG_SLOPE 0.2f

__device__ __forceinline__ float leaky(float a) { return a > 0.f ? a : NEG_SLOPE * a; }

// ---------------- pack: payload (ea1:f16|ea2:f16) + degree count + within-node rank ----------------
// ILP-4: each thread handles 4 edges (stride 256 within a 1024-edge block window) and issues
// all 4 rank atomicAdds back-to-back BEFORE the payload math. Pack is latency-bound on the
// far atomic (round-2 evidence: fused-kernel time matched the linear-concurrency model), so
// 4 atomics in flight per thread ~ 4x effective concurrency at full occupancy.
__global__ __launch_bounds__(256) void pack_edges(
    const int* __restrict__ dst, const float* __restrict__ eattr,
    const float* __restrict__ We1, const float* __restrict__ ae1,
    const float* __restrict__ We2, const float* __restrict__ ae2,
    int* __restrict__ deg, uint2* __restrict__ meta, int E) {
    __shared__ float wv[32];
    int t = threadIdx.x;
    if (t < 32) {
        const float* Wp = (t < 16) ? We1 : We2;
        const float* ap = (t < 16) ? ae1 : ae2;
        int f = t & 15;
        float s = 0.f;
        for (int k = 0; k < 64; ++k) s += Wp[f * 64 + k] * ap[k];
        wv[t] = s;
    }
    __syncthreads();

    int e0 = blockIdx.x * 1024 + threadIdx.x;
    int e1 = e0 + 256, e2 = e0 + 512, e3 = e0 + 768;
    bool v0 = e0 < E, v1 = e1 < E, v2 = e2 < E, v3 = e3 < E;

    // phase A: dst loads
    int d0 = 0, d1 = 0, d2 = 0, d3 = 0;
    if (v0) d0 = dst[e0];
    if (v1) d1 = dst[e1];
    if (v2) d2 = dst[e2];
    if (v3) d3 = dst[e3];
    // phase B: 4 atomics issued adjacently -> 4 in flight per thread
    int r0 = 0, r1 = 0, r2 = 0, r3 = 0;
    if (v0) r0 = atomicAdd(&deg[d0], 1);
    if (v1) r1 = atomicAdd(&deg[d1], 1);
    if (v2) r2 = atomicAdd(&deg[d2], 1);
    if (v3) r3 = atomicAdd(&deg[d3], 1);

    // phase C: payload math (overlaps atomic latency)
    unsigned int pw[4];
    int es[4] = {e0, e1, e2, e3};
    bool vs[4] = {v0, v1, v2, v3};
#pragma unroll
    for (int u = 0; u < 4; ++u) {
        if (!vs[u]) { pw[u] = 0; continue; }
        const float4* ep = (const float4*)(eattr + (size_t)es[u] * 16);
        float4 q0 = ep[0], q1 = ep[1], q2 = ep[2], q3 = ep[3];
        float a[16] = {q0.x, q0.y, q0.z, q0.w, q1.x, q1.y, q1.z, q1.w,
                       q2.x, q2.y, q2.z, q2.w, q3.x, q3.y, q3.z, q3.w};
        float s1 = 0.f, s2 = 0.f;
#pragma unroll
        for (int f = 0; f < 16; ++f) { s1 += a[f] * wv[f]; s2 += a[f] * wv[16 + f]; }
        unsigned int p1 = (unsigned int)__half_as_ushort(__float2half_rn(s1));
        unsigned int p2 = (unsigned int)__half_as_ushort(__float2half_rn(s2));
        pw[u] = p1 | (p2 << 16);
    }

    // phase D: stores (first point that waits on the atomics' return values)
    if (v0) meta[e0] = make_uint2(pw[0], (unsigned int)r0);
    if (v1) meta[e1] = make_uint2(pw[1], (unsigned int)r1);
    if (v2) meta[e2] = make_uint2(pw[2], (unsigned int)r2);
    if (v3) meta[e3] = make_uint2(pw[3], (unsigned int)r3);
}

// ---------------- scan: deg -> rowptr (block scan + per-block bsum prefix in finalize) ----------------
__global__ void scan_blocks(const int* __restrict__ deg, int* __restrict__ rowptr,
                            int* __restrict__ bsum, int n) {
    __shared__ int sh[1024];
    int i = blockIdx.x * 1024 + threadIdx.x;
    sh[threadIdx.x] = (i < n) ? deg[i] : 0;
    __syncthreads();
    for (int off = 1; off < 1024; off <<= 1) {
        int t = (threadIdx.x >= off) ? sh[threadIdx.x - off] : 0;
        __syncthreads();
        sh[threadIdx.x] += t;
        __syncthreads();
    }
    if (i < n) rowptr[i + 1] = sh[threadIdx.x];  // inclusive, pre-offset
    if (threadIdx.x == 1023) bsum[blockIdx.x] = sh[1023];
}

// each block b computes prefix = sum(bsum[0..b-1]) itself (nb ~ 98, cheap) then offsets 1024 rows
__global__ __launch_bounds__(256) void scan_finalize(int* __restrict__ rowptr,
                                                     const int* __restrict__ bsum, int n) {
    int b = blockIdx.x;
    int local = 0;
    for (int k = threadIdx.x; k < b; k += 256) local += bsum[k];
#pragma unroll
    for (int off = 1; off < 64; off <<= 1) local += __shfl_xor(local, off);
    __shared__ int ws4[4];
    if ((threadIdx.x & 63) == 0) ws4[threadIdx.x >> 6] = local;
    __syncthreads();
    int total = ws4[0] + ws4[1] + ws4[2] + ws4[3];
    for (int r = threadIdx.x; r < 1024; r += 256) {
        int i = b * 1024 + r;
        if (i < n) rowptr[i + 1] += total;
    }
    if (b == 0 && threadIdx.x == 0) rowptr[0] = 0;
}

// ---------------- route: atomic-free XCD-local CSR scatter ----------------
__global__ __launch_bounds__(256) void route_edges(
    const int* __restrict__ src, const int* __restrict__ dst,
    const uint2* __restrict__ meta, const int* __restrict__ rowptr,
    uint2* __restrict__ recs, int E, int slice_sz) {
    int xcd = blockIdx.x & 7;
    int team = blockIdx.x >> 3;
    int teams = gridDim.x >> 3;
    int lo = xcd * slice_sz, hi = lo + slice_sz;
    for (int e = team * 256 + threadIdx.x; e < E; e += teams * 256) {
        int d = dst[e];
        if (d < lo || d >= hi) continue;
        uint2 m = meta[e];
        int pos = rowptr[d] + (int)m.y;
        recs[pos] = make_uint2((unsigned int)src[e], m.x);
    }
}

// ---------------- node GEMM: h = X@W (K x 64) -> f16 rows, plus ash/adh (f32) ----------------
// Register-tiled: block = 128 rows x 64 cols, 256 threads, thread = 4 rows x 8 cols.
template <int K>
__global__ __launch_bounds__(256) void gemm_node(const float* __restrict__ X,
                                                 const float* __restrict__ W,
                                                 const float* __restrict__ a_s,
                                                 const float* __restrict__ a_d,
                                                 __half* __restrict__ Hout16,
                                                 float* __restrict__ ash,
                                                 float* __restrict__ adh, int n) {
    constexpr int KC = 64;
    __shared__ float xs[128 * 65];
    __shared__ float ws[KC * 64];
    int tid = threadIdx.x;
    int base = blockIdx.x * 128;
    int ct = tid & 7;
    int rt = tid >> 3;

    float acc[4][8];
#pragma unroll
    for (int i = 0; i < 4; ++i)
#pragma unroll
        for (int j = 0; j < 8; ++j) acc[i][j] = 0.f;

    for (int kc = 0; kc < K; kc += KC) {
#pragma unroll
        for (int p = 0; p < 8; ++p) {
            int idx = p * 256 + tid;
            int row = idx >> 4;
            int f4 = idx & 15;
            float4 q = make_float4(0.f, 0.f, 0.f, 0.f);
            if (base + row < n) q = *(const float4*)(X + (size_t)(base + row) * K + kc + f4 * 4);
            float* dp = xs + row * 65 + f4 * 4;
            dp[0] = q.x; dp[1] = q.y; dp[2] = q.z; dp[3] = q.w;
        }
#pragma unroll
        for (int p = 0; p < 4; ++p) {
            int idx = p * 256 + tid;
            int f = idx >> 4;
            int c4 = idx & 15;
            *(float4*)(ws + f * 64 + c4 * 4) =
                *(const float4*)(W + (size_t)(kc + f) * 64 + c4 * 4);
        }
        __syncthreads();
#pragma unroll 4
        for (int f = 0; f < KC; ++f) {
            float4 w0 = *(const float4*)(ws + f * 64 + ct * 8);
            float4 w1 = *(const float4*)(ws + f * 64 + ct * 8 + 4);
            float b0[8] = {w0.x, w0.y, w0.z, w0.w, w1.x, w1.y, w1.z, w1.w};
#pragma unroll
            for (int i = 0; i < 4; ++i) {
                float a = xs[(rt * 4 + i) * 65 + f];
#pragma unroll
                for (int j = 0; j < 8; ++j) acc[i][j] = fmaf(a, b0[j], acc[i][j]);
            }
        }
        __syncthreads();
    }

    float as_r[8], ad_r[8];
#pragma unroll
    for (int j = 0; j < 8; ++j) { as_r[j] = a_s[ct * 8 + j]; ad_r[j] = a_d[ct * 8 + j]; }
#pragma unroll
    for (int i = 0; i < 4; ++i) {
        int r = base + rt * 4 + i;
        float ps = 0.f, pd = 0.f;
#pragma unroll
        for (int j = 0; j < 8; ++j) {
            ps = fmaf(acc[i][j], as_r[j], ps);
            pd = fmaf(acc[i][j], ad_r[j], pd);
        }
        ps += __shfl_xor(ps, 1); pd += __shfl_xor(pd, 1);
        ps += __shfl_xor(ps, 2); pd += __shfl_xor(pd, 2);
        ps += __shfl_xor(ps, 4); pd += __shfl_xor(pd, 4);
        if (r < n) {
            union { __half h[8]; uint4 u; } pk;
#pragma unroll
            for (int j = 0; j < 8; ++j) pk.h[j] = __float2half_rn(acc[i][j]);
            *(uint4*)(Hout16 + (size_t)r * 64 + ct * 8) = pk.u;
            if (ct == 0) { ash[r] = ps; adh[r] = pd; }
        }
    }
}

// ---------------- GAT aggregation: one wave per destination node ----------------
// phase 1: lane l computes alpha/exp for edge c+l (one exp per EDGE);
// phase 2: broadcast (src, p) via v_readlane; per-lane work = 1 load + 1 cvt + 1 fma.
template <int LAYER>
__global__ __launch_bounds__(256) void gat_aggregate(
    const __half* __restrict__ Hf, const float* __restrict__ ash, const float* __restrict__ adh,
    const int* __restrict__ rowptr, const uint2* __restrict__ recs,
    const float* __restrict__ bias, float* __restrict__ outp, int n) {
    int wave = threadIdx.x >> 6;
    int lane = threadIdx.x & 63;
    int i = blockIdx.x * 4 + wave;
    if (i >= n) return;
    int start = rowptr[i], end = rowptr[i + 1];
    float adi = adh[i];

    float acc = 0.f;
    float zl = 0.f, seal = 0.f;

    for (int c = start; c < end; c += 64) {
        int cnt = min(64, end - c);
        int s_l = 0;
        float p_l = 0.f;
        if (lane < cnt) {
            uint2 r = recs[c + lane];
            s_l = (int)r.x;
            unsigned short u = (LAYER == 0) ? (unsigned short)(r.y & 0xffffu)
                                            : (unsigned short)(r.y >> 16);
            float e = __half2float(__ushort_as_half(u));
            float p = __expf(leaky(ash[s_l] + adi + e));
            p_l = p;
            zl += p;
            seal += e;
        }
        int k = 0;
        for (; k + 4 <= cnt; k += 4) {
            int s0 = __builtin_amdgcn_readlane(s_l, k);
            int s1 = __builtin_amdgcn_readlane(s_l, k + 1);
            int s2 = __builtin_amdgcn_readlane(s_l, k + 2);
            int s3 = __builtin_amdgcn_readlane(s_l, k + 3);
            float p0 = __uint_as_float(__builtin_amdgcn_readlane((int)__float_as_uint(p_l), k));
            float p1 = __uint_as_float(__builtin_amdgcn_readlane((int)__float_as_uint(p_l), k + 1));
            float p2 = __uint_as_float(__builtin_amdgcn_readlane((int)__float_as_uint(p_l), k + 2));
            float p3 = __uint_as_float(__builtin_amdgcn_readlane((int)__float_as_uint(p_l), k + 3));
            float v0 = __half2float(Hf[(size_t)s0 * 64 + lane]);
            float v1 = __half2float(Hf[(size_t)s1 * 64 + lane]);
            float v2 = __half2float(Hf[(size_t)s2 * 64 + lane]);
            float v3 = __half2float(Hf[(size_t)s3 * 64 + lane]);
            acc = fmaf(p0, v0, acc);
            acc = fmaf(p1, v1, acc);
            acc = fmaf(p2, v2, acc);
            acc = fmaf(p3, v3, acc);
        }
        for (; k < cnt; ++k) {
            int s0 = __builtin_amdgcn_readlane(s_l, k);
            float p0 = __uint_as_float(__builtin_amdgcn_readlane((int)__float_as_uint(p_l), k));
            float v0 = __half2float(Hf[(size_t)s0 * 64 + lane]);
            acc = fmaf(p0, v0, acc);
        }
    }

    float z = zl, sea = seal;
#pragma unroll
    for (int off = 1; off < 64; off <<= 1) {
        z += __shfl_xor(z, off);
        sea += __shfl_xor(sea, off);
    }

    int d = end - start;
    float loop_sc = sea / (float)max(d, 1);
    float aself = leaky(ash[i] + adi + loop_sc);
    float pself = __expf(aself);
    z += pself;
    acc = fmaf(pself, __half2float(Hf[(size_t)i * 64 + lane]), acc);
    float o = acc / z + bias[lane];
    outp[(size_t)i * 64 + lane] = fmaxf(o, 0.f);
}

// ---------------- classifier MLP: relu(X@Wc1+bc1)@Wc2+bc2 ----------------
__global__ __launch_bounds__(256) void mlp_kernel(const float* __restrict__ X,
                                                  const float* __restrict__ Wc1,
                                                  const float* __restrict__ bc1,
                                                  const float* __restrict__ Wc2,
                                                  const float* __restrict__ bc2,
                                                  float* __restrict__ outp, int n) {
    __shared__ float v[8 * 64];
    __shared__ float tb[8 * 32];
    int base = blockIdx.x * 8;
    for (int t = threadIdx.x; t < 512; t += 256) {
        int r = t >> 6;
        v[t] = (base + r < n) ? X[(size_t)base * 64 + t] : 0.f;
    }
    __syncthreads();
    int r = threadIdx.x >> 5, j = threadIdx.x & 31;
    float acc = bc1[j];
#pragma unroll
    for (int k = 0; k < 64; ++k) acc += v[r * 64 + k] * Wc1[k * 32 + j];
    acc = fmaxf(acc, 0.f);
    tb[r * 32 + j] = acc;
    __syncthreads();
    float lg = bc2[j];
#pragma unroll
    for (int k2 = 0; k2 < 32; ++k2) lg += tb[r * 32 + k2] * Wc2[k2 * 32 + j];
    int row = base + r;
    if (row < n) outp[(size_t)row * 32 + j] = lg;
}

extern "C" void kernel_launch(void* const* d_in, const int* in_sizes, int n_in,
                              void* d_out, int out_size, void* d_ws, size_t ws_size,
                              hipStream_t stream) {
    const float* x    = (const float*)d_in[0];
    const int*   ei   = (const int*)d_in[1];
    const float* eatt = (const float*)d_in[2];
    const float* W1   = (const float*)d_in[3];
    const float* as1  = (const float*)d_in[4];
    const float* ad1  = (const float*)d_in[5];
    const float* We1  = (const float*)d_in[6];
    const float* ae1  = (const float*)d_in[7];
    const float* b1   = (const float*)d_in[8];
    const float* W2   = (const float*)d_in[9];
    const float* as2  = (const float*)d_in[10];
    const float* ad2  = (const float*)d_in[11];
    const float* We2  = (const float*)d_in[12];
    const float* ae2  = (const float*)d_in[13];
    const float* b2   = (const float*)d_in[14];
    const float* Wc1  = (const float*)d_in[15];
    const float* bc1  = (const float*)d_in[16];
    const float* Wc2  = (const float*)d_in[17];
    const float* bc2  = (const float*)d_in[18];

    int n = in_sizes[0] / 128;
    int E = in_sizes[1] / 2;
    const int* src = ei;
    const int* dst = ei + E;

    // workspace carve (256B aligned)
    char* w = (char*)d_ws;
    auto alloc = [&](size_t bytes) { void* p = (void*)w; w += (bytes + 255) & ~(size_t)255; return p; };
    int* rowptr  = (int*)alloc((size_t)(n + 1) * 4);
    int* deg     = (int*)alloc((size_t)n * 4);
    int nb = (n + 1023) / 1024;
    int* bsum    = (int*)alloc((size_t)nb * 4);
    uint2* recs  = (uint2*)alloc((size_t)E * 8);
    uint2* meta  = (uint2*)alloc((size_t)E * 8);
    __half* hbuf16 = (__half*)alloc((size_t)n * 64 * 2);
    float* obuf  = (float*)alloc((size_t)n * 64 * 4);
    float* ash   = (float*)alloc((size_t)n * 4);
    float* adh   = (float*)alloc((size_t)n * 4);

    int slice_sz = (n + 7) / 8;

    hipMemsetAsync(deg, 0, (size_t)n * 4, stream);
    pack_edges<<<(E + 1023) / 1024, 256, 0, stream>>>(dst, eatt, We1, ae1, We2, ae2, deg, meta, E);
    scan_blocks<<<nb, 1024, 0, stream>>>(deg, rowptr, bsum, n);
    scan_finalize<<<nb, 256, 0, stream>>>(rowptr, bsum, n);
    route_edges<<<1024, 256, 0, stream>>>(src, dst, meta, rowptr, recs, E, slice_sz);

    // layer 1
    gemm_node<128><<<(n + 127) / 128, 256, 0, stream>>>(x, W1, as1, ad1, hbuf16, ash, adh, n);
    gat_aggregate<0><<<(n + 3) / 4, 256, 0, stream>>>(hbuf16, ash, adh, rowptr, recs, b1, obuf, n);
    // layer 2
    gemm_node<64><<<(n + 127) / 128, 256, 0, stream>>>(obuf, W2, as2, ad2, hbuf16, ash, adh, n);
    gat_aggregate<1><<<(n + 3) / 4, 256, 0, stream>>>(hbuf16, ash, adh, rowptr, recs, b2, obuf, n);
    // classifier
    mlp_kernel<<<(n + 7) / 8, 256, 0, stream>>>(obuf, Wc1, bc1, Wc2, bc2, (float*)d_out, n);
}

// Round 4
// 496.801 us; speedup vs baseline: 1.0695x; 1.0695x over previous
//
#include <hip/hip_runtime.h>
#include <hip/hip_bf16.h>
#include <hip/hip_fp16.h>

#define NEG_SLOPE 0.2f
// CSR build geometry: 512 dst-buckets of 256 nodes (assumes n <= 131072),
// 8192 edges per counting block (assumes E <= 8192*256 = 2.09M).
#define EPB 8192
#define NBUK 512

__device__ __forceinline__ float leaky(float a) { return a > 0.f ? a : NEG_SLOPE * a; }

// ---------------- K1: per-block bucket histogram + edge payload (f16|f16) ----------------
// No global atomics: LDS histogram only. Payload computed once here.
__global__ __launch_bounds__(256) void count_pack(
    const int* __restrict__ dst, const float* __restrict__ eattr,
    const float* __restrict__ We1, const float* __restrict__ ae1,
    const float* __restrict__ We2, const float* __restrict__ ae2,
    unsigned int* __restrict__ meta_pay, int* __restrict__ counts, int E) {
    __shared__ float wvs[32];
    __shared__ int hist[NBUK];
    int tid = threadIdx.x, i = blockIdx.x;
    if (tid < 32) {
        const float* Wp = (tid < 16) ? We1 : We2;
        const float* ap = (tid < 16) ? ae1 : ae2;
        int f = tid & 15;
        float s = 0.f;
        for (int k = 0; k < 64; ++k) s += Wp[f * 64 + k] * ap[k];
        wvs[tid] = s;
    }
    for (int t = tid; t < NBUK; t += 256) hist[t] = 0;
    __syncthreads();
    int e0 = i * EPB, e1 = min(E, e0 + EPB);
    for (int e = e0 + tid; e < e1; e += 256) {
        int d = dst[e];
        atomicAdd(&hist[d >> 8], 1);
        const float4* ep = (const float4*)(eattr + (size_t)e * 16);
        float4 q0 = ep[0], q1 = ep[1], q2 = ep[2], q3 = ep[3];
        float a[16] = {q0.x, q0.y, q0.z, q0.w, q1.x, q1.y, q1.z, q1.w,
                       q2.x, q2.y, q2.z, q2.w, q3.x, q3.y, q3.z, q3.w};
        float s1 = 0.f, s2 = 0.f;
#pragma unroll
        for (int f = 0; f < 16; ++f) { s1 += a[f] * wvs[f]; s2 += a[f] * wvs[16 + f]; }
        unsigned int p1 = (unsigned int)__half_as_ushort(__float2half_rn(s1));
        unsigned int p2 = (unsigned int)__half_as_ushort(__float2half_rn(s2));
        meta_pay[e] = p1 | (p2 << 16);
    }
    __syncthreads();
    for (int t = tid; t < NBUK; t += 256) counts[(size_t)i * NBUK + t] = hist[t];
}

// ---------------- K2a: per-bucket exclusive scan over blocks ----------------
// block b scans counts[*][b] (nblk <= 256) -> offsets[*][b], btot[b]
__global__ __launch_bounds__(256) void scan_cols(const int* __restrict__ counts,
                                                 int* __restrict__ offsets,
                                                 int* __restrict__ btot, int nblk) {
    __shared__ int sh[256];
    int b = blockIdx.x, t = threadIdx.x;
    int v = (t < nblk) ? counts[(size_t)t * NBUK + b] : 0;
    sh[t] = v;
    __syncthreads();
    for (int off = 1; off < 256; off <<= 1) {
        int u = (t >= off) ? sh[t - off] : 0;
        __syncthreads();
        sh[t] += u;
        __syncthreads();
    }
    if (t < nblk) offsets[(size_t)t * NBUK + b] = sh[t] - v;
    if (t == 255) btot[b] = sh[255];
}

// ---------------- K2b: exclusive scan of 512 bucket totals -> bucket bases ----------------
__global__ void scan_buckets(const int* __restrict__ btot, int* __restrict__ bbase,
                             int* __restrict__ rowptr, int E, int n) {
    __shared__ int sh[NBUK];
    int t = threadIdx.x;
    int v = btot[t];
    sh[t] = v;
    __syncthreads();
    for (int off = 1; off < NBUK; off <<= 1) {
        int u = (t >= off) ? sh[t - off] : 0;
        __syncthreads();
        sh[t] += u;
        __syncthreads();
    }
    bbase[t] = sh[t] - v;
    if (t == 0) rowptr[n] = E;
}

// ---------------- K3: scatter edges into dst-bucketed array (LDS cursors only) ----------------
// rec.x = src | (d_local << 24)   (assumes n < 2^24), rec.y = payload
__global__ __launch_bounds__(256) void scatter_buckets(
    const int* __restrict__ dst, const int* __restrict__ src,
    const unsigned int* __restrict__ meta_pay, const int* __restrict__ offsets,
    const int* __restrict__ bbase, uint2* __restrict__ bucketed, int E) {
    __shared__ int cur[NBUK];
    int i = blockIdx.x, tid = threadIdx.x;
    for (int t = tid; t < NBUK; t += 256) cur[t] = bbase[t] + offsets[(size_t)i * NBUK + t];
    __syncthreads();
    int e0 = i * EPB, e1 = min(E, e0 + EPB);
    for (int e = e0 + tid; e < e1; e += 256) {
        int d = dst[e];
        int slot = atomicAdd(&cur[d >> 8], 1);
        bucketed[slot] = make_uint2((unsigned int)src[e] | ((unsigned int)(d & 255) << 24),
                                    meta_pay[e]);
    }
}

// ---------------- K4: per-bucket degree count + LDS scan -> rowptr + final CSR recs ----------------
__global__ __launch_bounds__(256) void csr_build(const uint2* __restrict__ bucketed,
                                                 const int* __restrict__ bbase,
                                                 const int* __restrict__ btot,
                                                 int* __restrict__ rowptr,
                                                 uint2* __restrict__ recs, int n) {
    __shared__ int deg[256], sc[256], cur[256];
    int b = blockIdx.x, tid = threadIdx.x;
    int base = bbase[b], cnt = btot[b];
    deg[tid] = 0;
    __syncthreads();
    for (int k = tid; k < cnt; k += 256) {
        uint2 r = bucketed[base + k];
        atomicAdd(&deg[r.x >> 24], 1);
    }
    __syncthreads();
    int dv = deg[tid];
    sc[tid] = dv;
    __syncthreads();
    for (int off = 1; off < 256; off <<= 1) {
        int u = (tid >= off) ? sc[tid - off] : 0;
        __syncthreads();
        sc[tid] += u;
        __syncthreads();
    }
    int excl = sc[tid] - dv;
    int d = b * 256 + tid;
    if (d < n) rowptr[d] = base + excl;
    cur[tid] = base + excl;
    __syncthreads();
    for (int k = tid; k < cnt; k += 256) {
        uint2 r = bucketed[base + k];
        int dl = (int)(r.x >> 24);
        int pos = atomicAdd(&cur[dl], 1);
        recs[pos] = make_uint2(r.x & 0x00FFFFFFu, r.y);
    }
}

// ---------------- node GEMM: h = X@W (K x 64) -> f16 rows, plus ash/adh (f32) ----------------
template <int K>
__global__ __launch_bounds__(256) void gemm_node(const float* __restrict__ X,
                                                 const float* __restrict__ W,
                                                 const float* __restrict__ a_s,
                                                 const float* __restrict__ a_d,
                                                 __half* __restrict__ Hout16,
                                                 float* __restrict__ ash,
                                                 float* __restrict__ adh, int n) {
    constexpr int KC = 64;
    __shared__ float xs[128 * 65];
    __shared__ float ws[KC * 64];
    int tid = threadIdx.x;
    int base = blockIdx.x * 128;
    int ct = tid & 7;
    int rt = tid >> 3;

    float acc[4][8];
#pragma unroll
    for (int i = 0; i < 4; ++i)
#pragma unroll
        for (int j = 0; j < 8; ++j) acc[i][j] = 0.f;

    for (int kc = 0; kc < K; kc += KC) {
#pragma unroll
        for (int p = 0; p < 8; ++p) {
            int idx = p * 256 + tid;
            int row = idx >> 4;
            int f4 = idx & 15;
            float4 q = make_float4(0.f, 0.f, 0.f, 0.f);
            if (base + row < n) q = *(const float4*)(X + (size_t)(base + row) * K + kc + f4 * 4);
            float* dp = xs + row * 65 + f4 * 4;
            dp[0] = q.x; dp[1] = q.y; dp[2] = q.z; dp[3] = q.w;
        }
#pragma unroll
        for (int p = 0; p < 4; ++p) {
            int idx = p * 256 + tid;
            int f = idx >> 4;
            int c4 = idx & 15;
            *(float4*)(ws + f * 64 + c4 * 4) =
                *(const float4*)(W + (size_t)(kc + f) * 64 + c4 * 4);
        }
        __syncthreads();
#pragma unroll 4
        for (int f = 0; f < KC; ++f) {
            float4 w0 = *(const float4*)(ws + f * 64 + ct * 8);
            float4 w1 = *(const float4*)(ws + f * 64 + ct * 8 + 4);
            float b0[8] = {w0.x, w0.y, w0.z, w0.w, w1.x, w1.y, w1.z, w1.w};
#pragma unroll
            for (int i = 0; i < 4; ++i) {
                float a = xs[(rt * 4 + i) * 65 + f];
#pragma unroll
                for (int j = 0; j < 8; ++j) acc[i][j] = fmaf(a, b0[j], acc[i][j]);
            }
        }
        __syncthreads();
    }

    float as_r[8], ad_r[8];
#pragma unroll
    for (int j = 0; j < 8; ++j) { as_r[j] = a_s[ct * 8 + j]; ad_r[j] = a_d[ct * 8 + j]; }
#pragma unroll
    for (int i = 0; i < 4; ++i) {
        int r = base + rt * 4 + i;
        float ps = 0.f, pd = 0.f;
#pragma unroll
        for (int j = 0; j < 8; ++j) {
            ps = fmaf(acc[i][j], as_r[j], ps);
            pd = fmaf(acc[i][j], ad_r[j], pd);
        }
        ps += __shfl_xor(ps, 1); pd += __shfl_xor(pd, 1);
        ps += __shfl_xor(ps, 2); pd += __shfl_xor(pd, 2);
        ps += __shfl_xor(ps, 4); pd += __shfl_xor(pd, 4);
        if (r < n) {
            union { __half h[8]; uint4 u; } pk;
#pragma unroll
            for (int j = 0; j < 8; ++j) pk.h[j] = __float2half_rn(acc[i][j]);
            *(uint4*)(Hout16 + (size_t)r * 64 + ct * 8) = pk.u;
            if (ct == 0) { ash[r] = ps; adh[r] = pd; }
        }
    }
}

// ---------------- GAT aggregation: one wave per destination node ----------------
// phase 1: lane l computes alpha/exp for edge c+l (one exp per EDGE);
// phase 2: broadcast (src, p) via v_readlane; per-lane work = 1 load + 1 cvt + 1 fma.
template <int LAYER>
__global__ __launch_bounds__(256) void gat_aggregate(
    const __half* __restrict__ Hf, const float* __restrict__ ash, const float* __restrict__ adh,
    const int* __restrict__ rowptr, const uint2* __restrict__ recs,
    const float* __restrict__ bias, float* __restrict__ outp, int n) {
    int wave = threadIdx.x >> 6;
    int lane = threadIdx.x & 63;
    int i = blockIdx.x * 4 + wave;
    if (i >= n) return;
    int start = rowptr[i], end = rowptr[i + 1];
    float adi = adh[i];

    float acc = 0.f;
    float zl = 0.f, seal = 0.f;

    for (int c = start; c < end; c += 64) {
        int cnt = min(64, end - c);
        int s_l = 0;
        float p_l = 0.f;
        if (lane < cnt) {
            uint2 r = recs[c + lane];
            s_l = (int)r.x;
            unsigned short u = (LAYER == 0) ? (unsigned short)(r.y & 0xffffu)
                                            : (unsigned short)(r.y >> 16);
            float e = __half2float(__ushort_as_half(u));
            float p = __expf(leaky(ash[s_l] + adi + e));
            p_l = p;
            zl += p;
            seal += e;
        }
        int k = 0;
        for (; k + 4 <= cnt; k += 4) {
            int s0 = __builtin_amdgcn_readlane(s_l, k);
            int s1 = __builtin_amdgcn_readlane(s_l, k + 1);
            int s2 = __builtin_amdgcn_readlane(s_l, k + 2);
            int s3 = __builtin_amdgcn_readlane(s_l, k + 3);
            float p0 = __uint_as_float(__builtin_amdgcn_readlane((int)__float_as_uint(p_l), k));
            float p1 = __uint_as_float(__builtin_amdgcn_readlane((int)__float_as_uint(p_l), k + 1));
            float p2 = __uint_as_float(__builtin_amdgcn_readlane((int)__float_as_uint(p_l), k + 2));
            float p3 = __uint_as_float(__builtin_amdgcn_readlane((int)__float_as_uint(p_l), k + 3));
            float v0 = __half2float(Hf[(size_t)s0 * 64 + lane]);
            float v1 = __half2float(Hf[(size_t)s1 * 64 + lane]);
            float v2 = __half2float(Hf[(size_t)s2 * 64 + lane]);
            float v3 = __half2float(Hf[(size_t)s3 * 64 + lane]);
            acc = fmaf(p0, v0, acc);
            acc = fmaf(p1, v1, acc);
            acc = fmaf(p2, v2, acc);
            acc = fmaf(p3, v3, acc);
        }
        for (; k < cnt; ++k) {
            int s0 = __builtin_amdgcn_readlane(s_l, k);
            float p0 = __uint_as_float(__builtin_amdgcn_readlane((int)__float_as_uint(p_l), k));
            float v0 = __half2float(Hf[(size_t)s0 * 64 + lane]);
            acc = fmaf(p0, v0, acc);
        }
    }

    float z = zl, sea = seal;
#pragma unroll
    for (int off = 1; off < 64; off <<= 1) {
        z += __shfl_xor(z, off);
        sea += __shfl_xor(sea, off);
    }

    int d = end - start;
    float loop_sc = sea / (float)max(d, 1);
    float aself = leaky(ash[i] + adi + loop_sc);
    float pself = __expf(aself);
    z += pself;
    acc = fmaf(pself, __half2float(Hf[(size_t)i * 64 + lane]), acc);
    float o = acc / z + bias[lane];
    outp[(size_t)i * 64 + lane] = fmaxf(o, 0.f);
}

// ---------------- classifier MLP: relu(X@Wc1+bc1)@Wc2+bc2 ----------------
__global__ __launch_bounds__(256) void mlp_kernel(const float* __restrict__ X,
                                                  const float* __restrict__ Wc1,
                                                  const float* __restrict__ bc1,
                                                  const float* __restrict__ Wc2,
                                                  const float* __restrict__ bc2,
                                                  float* __restrict__ outp, int n) {
    __shared__ float v[8 * 64];
    __shared__ float tb[8 * 32];
    int base = blockIdx.x * 8;
    for (int t = threadIdx.x; t < 512; t += 256) {
        int r = t >> 6;
        v[t] = (base + r < n) ? X[(size_t)base * 64 + t] : 0.f;
    }
    __syncthreads();
    int r = threadIdx.x >> 5, j = threadIdx.x & 31;
    float acc = bc1[j];
#pragma unroll
    for (int k = 0; k < 64; ++k) acc += v[r * 64 + k] * Wc1[k * 32 + j];
    acc = fmaxf(acc, 0.f);
    tb[r * 32 + j] = acc;
    __syncthreads();
    float lg = bc2[j];
#pragma unroll
    for (int k2 = 0; k2 < 32; ++k2) lg += tb[r * 32 + k2] * Wc2[k2 * 32 + j];
    int row = base + r;
    if (row < n) outp[(size_t)row * 32 + j] = lg;
}

extern "C" void kernel_launch(void* const* d_in, const int* in_sizes, int n_in,
                              void* d_out, int out_size, void* d_ws, size_t ws_size,
                              hipStream_t stream) {
    const float* x    = (const float*)d_in[0];
    const int*   ei   = (const int*)d_in[1];
    const float* eatt = (const float*)d_in[2];
    const float* W1   = (const float*)d_in[3];
    const float* as1  = (const float*)d_in[4];
    const float* ad1  = (const float*)d_in[5];
    const float* We1  = (const float*)d_in[6];
    const float* ae1  = (const float*)d_in[7];
    const float* b1   = (const float*)d_in[8];
    const float* W2   = (const float*)d_in[9];
    const float* as2  = (const float*)d_in[10];
    const float* ad2  = (const float*)d_in[11];
    const float* We2  = (const float*)d_in[12];
    const float* ae2  = (const float*)d_in[13];
    const float* b2   = (const float*)d_in[14];
    const float* Wc1  = (const float*)d_in[15];
    const float* bc1  = (const float*)d_in[16];
    const float* Wc2  = (const float*)d_in[17];
    const float* bc2  = (const float*)d_in[18];

    int n = in_sizes[0] / 128;
    int E = in_sizes[1] / 2;
    const int* src = ei;
    const int* dst = ei + E;
    int nblk = (E + EPB - 1) / EPB;  // must be <= 256 (E <= 2.09M)

    // workspace carve (256B aligned)
    char* w = (char*)d_ws;
    auto alloc = [&](size_t bytes) { void* p = (void*)w; w += (bytes + 255) & ~(size_t)255; return p; };
    int* rowptr   = (int*)alloc((size_t)(n + 1) * 4);
    int* counts   = (int*)alloc((size_t)nblk * NBUK * 4);
    int* offsets  = (int*)alloc((size_t)nblk * NBUK * 4);
    int* btot     = (int*)alloc((size_t)NBUK * 4);
    int* bbase    = (int*)alloc((size_t)NBUK * 4);
    unsigned int* meta_pay = (unsigned int*)alloc((size_t)E * 4);
    uint2* recs   = (uint2*)alloc((size_t)E * 8);
    __half* hbuf16 = (__half*)alloc((size_t)n * 64 * 2);
    float* obuf   = (float*)alloc((size_t)n * 64 * 4);
    float* ash    = (float*)alloc((size_t)n * 4);
    float* adh    = (float*)alloc((size_t)n * 4);
    // bucketed edge array aliases obuf: it is dead before gat_aggregate<0> writes obuf
    // (E*8 = 12.8MB <= n*64*4 = 25.6MB)
    uint2* bucketed = (uint2*)obuf;

    // ---- CSR build: no global returning atomics anywhere ----
    count_pack<<<nblk, 256, 0, stream>>>(dst, eatt, We1, ae1, We2, ae2, meta_pay, counts, E);
    scan_cols<<<NBUK, 256, 0, stream>>>(counts, offsets, btot, nblk);
    scan_buckets<<<1, NBUK, 0, stream>>>(btot, bbase, rowptr, E, n);
    scatter_buckets<<<nblk, 256, 0, stream>>>(dst, src, meta_pay, offsets, bbase, bucketed, E);
    csr_build<<<NBUK, 256, 0, stream>>>(bucketed, bbase, btot, rowptr, recs, n);

    // layer 1
    gemm_node<128><<<(n + 127) / 128, 256, 0, stream>>>(x, W1, as1, ad1, hbuf16, ash, adh, n);
    gat_aggregate<0><<<(n + 3) / 4, 256, 0, stream>>>(hbuf16, ash, adh, rowptr, recs, b1, obuf, n);
    // layer 2
    gemm_node<64><<<(n + 127) / 128, 256, 0, stream>>>(obuf, W2, as2, ad2, hbuf16, ash, adh, n);
    gat_aggregate<1><<<(n + 3) / 4, 256, 0, stream>>>(hbuf16, ash, adh, rowptr, recs, b2, obuf, n);
    // classifier
    mlp_kernel<<<(n + 7) / 8, 256, 0, stream>>>(obuf, Wc1, bc1, Wc2, bc2, (float*)d_out, n);
}

// Round 5
// 485.929 us; speedup vs baseline: 1.0934x; 1.0224x over previous
//
#include <hip/hip_runtime.h>
#include <hip/hip_bf16.h>
#include <hip/hip_fp16.h>

#define NEG_SLOPE 0.2f
// CSR build geometry: 512 dst-buckets of 256 nodes (assumes n <= 131072),
// 2048 edges per counting block (assumes E <= 2048*1024 = 2.09M blocks-wise).
#define EPB 2048
#define NBUK 512

__device__ __forceinline__ float leaky(float a) { return a > 0.f ? a : NEG_SLOPE * a; }

// ---------------- K1: per-block bucket histogram + edge payload (f16|f16) ----------------
// No global atomics: LDS histogram only. Payload computed once here.
__global__ __launch_bounds__(256) void count_pack(
    const int* __restrict__ dst, const float* __restrict__ eattr,
    const float* __restrict__ We1, const float* __restrict__ ae1,
    const float* __restrict__ We2, const float* __restrict__ ae2,
    unsigned int* __restrict__ meta_pay, int* __restrict__ counts, int E) {
    __shared__ float wvs[32];
    __shared__ int hist[NBUK];
    int tid = threadIdx.x, i = blockIdx.x;
    if (tid < 32) {
        const float* Wp = (tid < 16) ? We1 : We2;
        const float* ap = (tid < 16) ? ae1 : ae2;
        int f = tid & 15;
        float s = 0.f;
        for (int k = 0; k < 64; ++k) s += Wp[f * 64 + k] * ap[k];
        wvs[tid] = s;
    }
    for (int t = tid; t < NBUK; t += 256) hist[t] = 0;
    __syncthreads();
    int e0 = i * EPB, e1 = min(E, e0 + EPB);
    for (int e = e0 + tid; e < e1; e += 256) {
        int d = dst[e];
        atomicAdd(&hist[d >> 8], 1);
        const float4* ep = (const float4*)(eattr + (size_t)e * 16);
        float4 q0 = ep[0], q1 = ep[1], q2 = ep[2], q3 = ep[3];
        float a[16] = {q0.x, q0.y, q0.z, q0.w, q1.x, q1.y, q1.z, q1.w,
                       q2.x, q2.y, q2.z, q2.w, q3.x, q3.y, q3.z, q3.w};
        float s1 = 0.f, s2 = 0.f;
#pragma unroll
        for (int f = 0; f < 16; ++f) { s1 += a[f] * wvs[f]; s2 += a[f] * wvs[16 + f]; }
        unsigned int p1 = (unsigned int)__half_as_ushort(__float2half_rn(s1));
        unsigned int p2 = (unsigned int)__half_as_ushort(__float2half_rn(s2));
        meta_pay[e] = p1 | (p2 << 16);
    }
    __syncthreads();
    for (int t = tid; t < NBUK; t += 256) counts[(size_t)i * NBUK + t] = hist[t];
}

// ---------------- K2a: per-bucket exclusive scan over blocks ----------------
// block b scans counts[*][b] (nblk <= 1024) -> offsets[*][b], btot[b]
__global__ __launch_bounds__(1024) void scan_cols(const int* __restrict__ counts,
                                                  int* __restrict__ offsets,
                                                  int* __restrict__ btot, int nblk) {
    __shared__ int sh[1024];
    int b = blockIdx.x, t = threadIdx.x;
    int v = (t < nblk) ? counts[(size_t)t * NBUK + b] : 0;
    sh[t] = v;
    __syncthreads();
    for (int off = 1; off < 1024; off <<= 1) {
        int u = (t >= off) ? sh[t - off] : 0;
        __syncthreads();
        sh[t] += u;
        __syncthreads();
    }
    if (t < nblk) offsets[(size_t)t * NBUK + b] = sh[t] - v;
    if (t == 1023) btot[b] = sh[1023];
}

// ---------------- K2b: exclusive scan of 512 bucket totals -> bucket bases ----------------
__global__ void scan_buckets(const int* __restrict__ btot, int* __restrict__ bbase,
                             int* __restrict__ rowptr, int E, int n) {
    __shared__ int sh[NBUK];
    int t = threadIdx.x;
    int v = btot[t];
    sh[t] = v;
    __syncthreads();
    for (int off = 1; off < NBUK; off <<= 1) {
        int u = (t >= off) ? sh[t - off] : 0;
        __syncthreads();
        sh[t] += u;
        __syncthreads();
    }
    bbase[t] = sh[t] - v;
    if (t == 0) rowptr[n] = E;
}

// ---------------- K3: scatter edges into dst-bucketed array (LDS cursors only) ----------------
// rec.x = src | (d_local << 24)   (assumes n < 2^24), rec.y = payload
__global__ __launch_bounds__(256) void scatter_buckets(
    const int* __restrict__ dst, const int* __restrict__ src,
    const unsigned int* __restrict__ meta_pay, const int* __restrict__ offsets,
    const int* __restrict__ bbase, uint2* __restrict__ bucketed, int E) {
    __shared__ int cur[NBUK];
    int i = blockIdx.x, tid = threadIdx.x;
    for (int t = tid; t < NBUK; t += 256) cur[t] = bbase[t] + offsets[(size_t)i * NBUK + t];
    __syncthreads();
    int e0 = i * EPB, e1 = min(E, e0 + EPB);
    for (int e = e0 + tid; e < e1; e += 256) {
        int d = dst[e];
        int slot = atomicAdd(&cur[d >> 8], 1);
        bucketed[slot] = make_uint2((unsigned int)src[e] | ((unsigned int)(d & 255) << 24),
                                    meta_pay[e]);
    }
}

// ---------------- K4: per-bucket degree count + LDS scan -> rowptr + final CSR recs ----------------
__global__ __launch_bounds__(256) void csr_build(const uint2* __restrict__ bucketed,
                                                 const int* __restrict__ bbase,
                                                 const int* __restrict__ btot,
                                                 int* __restrict__ rowptr,
                                                 uint2* __restrict__ recs, int n) {
    __shared__ int deg[256], sc[256], cur[256];
    int b = blockIdx.x, tid = threadIdx.x;
    int base = bbase[b], cnt = btot[b];
    deg[tid] = 0;
    __syncthreads();
    for (int k = tid; k < cnt; k += 256) {
        uint2 r = bucketed[base + k];
        atomicAdd(&deg[r.x >> 24], 1);
    }
    __syncthreads();
    int dv = deg[tid];
    sc[tid] = dv;
    __syncthreads();
    for (int off = 1; off < 256; off <<= 1) {
        int u = (tid >= off) ? sc[tid - off] : 0;
        __syncthreads();
        sc[tid] += u;
        __syncthreads();
    }
    int excl = sc[tid] - dv;
    int d = b * 256 + tid;
    if (d < n) rowptr[d] = base + excl;
    cur[tid] = base + excl;
    __syncthreads();
    for (int k = tid; k < cnt; k += 256) {
        uint2 r = bucketed[base + k];
        int dl = (int)(r.x >> 24);
        int pos = atomicAdd(&cur[dl], 1);
        recs[pos] = make_uint2(r.x & 0x00FFFFFFu, r.y);
    }
}

// ---------------- node GEMM: h = X@W (K x 64) -> f16 rows, plus ash/adh (f32) ----------------
template <int K>
__global__ __launch_bounds__(256) void gemm_node(const float* __restrict__ X,
                                                 const float* __restrict__ W,
                                                 const float* __restrict__ a_s,
                                                 const float* __restrict__ a_d,
                                                 __half* __restrict__ Hout16,
                                                 float* __restrict__ ash,
                                                 float* __restrict__ adh, int n) {
    constexpr int KC = 64;
    __shared__ float xs[128 * 65];
    __shared__ float ws[KC * 64];
    int tid = threadIdx.x;
    int base = blockIdx.x * 128;
    int ct = tid & 7;
    int rt = tid >> 3;

    float acc[4][8];
#pragma unroll
    for (int i = 0; i < 4; ++i)
#pragma unroll
        for (int j = 0; j < 8; ++j) acc[i][j] = 0.f;

    for (int kc = 0; kc < K; kc += KC) {
#pragma unroll
        for (int p = 0; p < 8; ++p) {
            int idx = p * 256 + tid;
            int row = idx >> 4;
            int f4 = idx & 15;
            float4 q = make_float4(0.f, 0.f, 0.f, 0.f);
            if (base + row < n) q = *(const float4*)(X + (size_t)(base + row) * K + kc + f4 * 4);
            float* dp = xs + row * 65 + f4 * 4;
            dp[0] = q.x; dp[1] = q.y; dp[2] = q.z; dp[3] = q.w;
        }
#pragma unroll
        for (int p = 0; p < 4; ++p) {
            int idx = p * 256 + tid;
            int f = idx >> 4;
            int c4 = idx & 15;
            *(float4*)(ws + f * 64 + c4 * 4) =
                *(const float4*)(W + (size_t)(kc + f) * 64 + c4 * 4);
        }
        __syncthreads();
#pragma unroll 4
        for (int f = 0; f < KC; ++f) {
            float4 w0 = *(const float4*)(ws + f * 64 + ct * 8);
            float4 w1 = *(const float4*)(ws + f * 64 + ct * 8 + 4);
            float b0[8] = {w0.x, w0.y, w0.z, w0.w, w1.x, w1.y, w1.z, w1.w};
#pragma unroll
            for (int i = 0; i < 4; ++i) {
                float a = xs[(rt * 4 + i) * 65 + f];
#pragma unroll
                for (int j = 0; j < 8; ++j) acc[i][j] = fmaf(a, b0[j], acc[i][j]);
            }
        }
        __syncthreads();
    }

    float as_r[8], ad_r[8];
#pragma unroll
    for (int j = 0; j < 8; ++j) { as_r[j] = a_s[ct * 8 + j]; ad_r[j] = a_d[ct * 8 + j]; }
#pragma unroll
    for (int i = 0; i < 4; ++i) {
        int r = base + rt * 4 + i;
        float ps = 0.f, pd = 0.f;
#pragma unroll
        for (int j = 0; j < 8; ++j) {
            ps = fmaf(acc[i][j], as_r[j], ps);
            pd = fmaf(acc[i][j], ad_r[j], pd);
        }
        ps += __shfl_xor(ps, 1); pd += __shfl_xor(pd, 1);
        ps += __shfl_xor(ps, 2); pd += __shfl_xor(pd, 2);
        ps += __shfl_xor(ps, 4); pd += __shfl_xor(pd, 4);
        if (r < n) {
            union { __half h[8]; uint4 u; } pk;
#pragma unroll
            for (int j = 0; j < 8; ++j) pk.h[j] = __float2half_rn(acc[i][j]);
            *(uint4*)(Hout16 + (size_t)r * 64 + ct * 8) = pk.u;
            if (ct == 0) { ash[r] = ps; adh[r] = pd; }
        }
    }
}

// ---------------- GAT aggregation: one wave per destination node ----------------
// phase 1: lane l computes alpha/exp for edge c+l (one exp per EDGE) and the BYTE
//          OFFSET of its value row (s<<7);
// phase 2: broadcast (byte_off, p) via v_readlane -> SGPRs; row pointer becomes
//          scalar math (s_add_u64), per-edge lane work = 1 load + cvt + fma.
template <int LAYER>
__global__ __launch_bounds__(256) void gat_aggregate(
    const __half* __restrict__ Hf, const float* __restrict__ ash, const float* __restrict__ adh,
    const int* __restrict__ rowptr, const uint2* __restrict__ recs,
    const float* __restrict__ bias, float* __restrict__ outp, int n) {
    int wave = threadIdx.x >> 6;
    int lane = threadIdx.x & 63;
    int i = blockIdx.x * 4 + wave;
    if (i >= n) return;
    int start = rowptr[i], end = rowptr[i + 1];
    float adi = adh[i];
    const char* Hb = (const char*)Hf;

    float acc = 0.f;
    float zl = 0.f, seal = 0.f;

    for (int c = start; c < end; c += 64) {
        int cnt = min(64, end - c);
        int o_l = 0;       // byte offset of src row (s * 128)
        float p_l = 0.f;
        if (lane < cnt) {
            uint2 r = recs[c + lane];
            int s_l = (int)r.x;
            o_l = s_l << 7;
            unsigned short u = (LAYER == 0) ? (unsigned short)(r.y & 0xffffu)
                                            : (unsigned short)(r.y >> 16);
            float e = __half2float(__ushort_as_half(u));
            float p = __expf(leaky(ash[s_l] + adi + e));
            p_l = p;
            zl += p;
            seal += e;
        }
        int k = 0;
        for (; k + 4 <= cnt; k += 4) {
            int o0 = __builtin_amdgcn_readlane(o_l, k);
            int o1 = __builtin_amdgcn_readlane(o_l, k + 1);
            int o2 = __builtin_amdgcn_readlane(o_l, k + 2);
            int o3 = __builtin_amdgcn_readlane(o_l, k + 3);
            float p0 = __uint_as_float(__builtin_amdgcn_readlane((int)__float_as_uint(p_l), k));
            float p1 = __uint_as_float(__builtin_amdgcn_readlane((int)__float_as_uint(p_l), k + 1));
            float p2 = __uint_as_float(__builtin_amdgcn_readlane((int)__float_as_uint(p_l), k + 2));
            float p3 = __uint_as_float(__builtin_amdgcn_readlane((int)__float_as_uint(p_l), k + 3));
            float v0 = __half2float(((const __half*)(Hb + o0))[lane]);
            float v1 = __half2float(((const __half*)(Hb + o1))[lane]);
            float v2 = __half2float(((const __half*)(Hb + o2))[lane]);
            float v3 = __half2float(((const __half*)(Hb + o3))[lane]);
            acc = fmaf(p0, v0, acc);
            acc = fmaf(p1, v1, acc);
            acc = fmaf(p2, v2, acc);
            acc = fmaf(p3, v3, acc);
        }
        for (; k < cnt; ++k) {
            int o0 = __builtin_amdgcn_readlane(o_l, k);
            float p0 = __uint_as_float(__builtin_amdgcn_readlane((int)__float_as_uint(p_l), k));
            float v0 = __half2float(((const __half*)(Hb + o0))[lane]);
            acc = fmaf(p0, v0, acc);
        }
    }

    float z = zl, sea = seal;
#pragma unroll
    for (int off = 1; off < 64; off <<= 1) {
        z += __shfl_xor(z, off);
        sea += __shfl_xor(sea, off);
    }

    int d = end - start;
    float loop_sc = sea / (float)max(d, 1);
    float aself = leaky(ash[i] + adi + loop_sc);
    float pself = __expf(aself);
    z += pself;
    acc = fmaf(pself, __half2float(Hf[(size_t)i * 64 + lane]), acc);
    float o = acc / z + bias[lane];
    outp[(size_t)i * 64 + lane] = fmaxf(o, 0.f);
}

// ---------------- classifier MLP: relu(X@Wc1+bc1)@Wc2+bc2 ----------------
__global__ __launch_bounds__(256) void mlp_kernel(const float* __restrict__ X,
                                                  const float* __restrict__ Wc1,
                                                  const float* __restrict__ bc1,
                                                  const float* __restrict__ Wc2,
                                                  const float* __restrict__ bc2,
                                                  float* __restrict__ outp, int n) {
    __shared__ float v[8 * 64];
    __shared__ float tb[8 * 32];
    int base = blockIdx.x * 8;
    for (int t = threadIdx.x; t < 512; t += 256) {
        int r = t >> 6;
        v[t] = (base + r < n) ? X[(size_t)base * 64 + t] : 0.f;
    }
    __syncthreads();
    int r = threadIdx.x >> 5, j = threadIdx.x & 31;
    float acc = bc1[j];
#pragma unroll
    for (int k = 0; k < 64; ++k) acc += v[r * 64 + k] * Wc1[k * 32 + j];
    acc = fmaxf(acc, 0.f);
    tb[r * 32 + j] = acc;
    __syncthreads();
    float lg = bc2[j];
#pragma unroll
    for (int k2 = 0; k2 < 32; ++k2) lg += tb[r * 32 + k2] * Wc2[k2 * 32 + j];
    int row = base + r;
    if (row < n) outp[(size_t)row * 32 + j] = lg;
}

extern "C" void kernel_launch(void* const* d_in, const int* in_sizes, int n_in,
                              void* d_out, int out_size, void* d_ws, size_t ws_size,
                              hipStream_t stream) {
    const float* x    = (const float*)d_in[0];
    const int*   ei   = (const int*)d_in[1];
    const float* eatt = (const float*)d_in[2];
    const float* W1   = (const float*)d_in[3];
    const float* as1  = (const float*)d_in[4];
    const float* ad1  = (const float*)d_in[5];
    const float* We1  = (const float*)d_in[6];
    const float* ae1  = (const float*)d_in[7];
    const float* b1   = (const float*)d_in[8];
    const float* W2   = (const float*)d_in[9];
    const float* as2  = (const float*)d_in[10];
    const float* ad2  = (const float*)d_in[11];
    const float* We2  = (const float*)d_in[12];
    const float* ae2  = (const float*)d_in[13];
    const float* b2   = (const float*)d_in[14];
    const float* Wc1  = (const float*)d_in[15];
    const float* bc1  = (const float*)d_in[16];
    const float* Wc2  = (const float*)d_in[17];
    const float* bc2  = (const float*)d_in[18];

    int n = in_sizes[0] / 128;
    int E = in_sizes[1] / 2;
    const int* src = ei;
    const int* dst = ei + E;
    int nblk = (E + EPB - 1) / EPB;  // must be <= 1024 (E <= 2.09M)

    // workspace carve (256B aligned)
    char* w = (char*)d_ws;
    auto alloc = [&](size_t bytes) { void* p = (void*)w; w += (bytes + 255) & ~(size_t)255; return p; };
    int* rowptr   = (int*)alloc((size_t)(n + 1) * 4);
    int* counts   = (int*)alloc((size_t)nblk * NBUK * 4);
    int* offsets  = (int*)alloc((size_t)nblk * NBUK * 4);
    int* btot     = (int*)alloc((size_t)NBUK * 4);
    int* bbase    = (int*)alloc((size_t)NBUK * 4);
    unsigned int* meta_pay = (unsigned int*)alloc((size_t)E * 4);
    uint2* recs   = (uint2*)alloc((size_t)E * 8);
    __half* hbuf16 = (__half*)alloc((size_t)n * 64 * 2);
    float* obuf   = (float*)alloc((size_t)n * 64 * 4);
    float* ash    = (float*)alloc((size_t)n * 4);
    float* adh    = (float*)alloc((size_t)n * 4);
    // bucketed edge array aliases obuf: it is dead before gat_aggregate<0> writes obuf
    // (E*8 = 12.8MB <= n*64*4 = 25.6MB)
    uint2* bucketed = (uint2*)obuf;

    // ---- CSR build: no global returning atomics anywhere ----
    count_pack<<<nblk, 256, 0, stream>>>(dst, eatt, We1, ae1, We2, ae2, meta_pay, counts, E);
    scan_cols<<<NBUK, 1024, 0, stream>>>(counts, offsets, btot, nblk);
    scan_buckets<<<1, NBUK, 0, stream>>>(btot, bbase, rowptr, E, n);
    scatter_buckets<<<nblk, 256, 0, stream>>>(dst, src, meta_pay, offsets, bbase, bucketed, E);
    csr_build<<<NBUK, 256, 0, stream>>>(bucketed, bbase, btot, rowptr, recs, n);

    // layer 1
    gemm_node<128><<<(n + 127) / 128, 256, 0, stream>>>(x, W1, as1, ad1, hbuf16, ash, adh, n);
    gat_aggregate<0><<<(n + 3) / 4, 256, 0, stream>>>(hbuf16, ash, adh, rowptr, recs, b1, obuf, n);
    // layer 2
    gemm_node<64><<<(n + 127) / 128, 256, 0, stream>>>(obuf, W2, as2, ad2, hbuf16, ash, adh, n);
    gat_aggregate<1><<<(n + 3) / 4, 256, 0, stream>>>(hbuf16, ash, adh, rowptr, recs, b2, obuf, n);
    // classifier
    mlp_kernel<<<(n + 7) / 8, 256, 0, stream>>>(obuf, Wc1, bc1, Wc2, bc2, (float*)d_out, n);
}

// Round 6
// 477.484 us; speedup vs baseline: 1.1128x; 1.0177x over previous
//
#include <hip/hip_runtime.h>
#include <hip/hip_bf16.h>
#include <hip/hip_fp16.h>

#define NEG_SLOPE 0.2f
// CSR build geometry: 512 dst-buckets of 256 nodes (assumes n <= 131072),
// 2048 edges per counting block (assumes E <= 2048*1024 = 2.09M blocks-wise).
#define EPB 2048
#define NBUK 512

__device__ __forceinline__ float leaky(float a) { return a > 0.f ? a : NEG_SLOPE * a; }

// ---------------- K1: per-block bucket histogram + edge payload (f16|f16) ----------------
__global__ __launch_bounds__(256) void count_pack(
    const int* __restrict__ dst, const float* __restrict__ eattr,
    const float* __restrict__ We1, const float* __restrict__ ae1,
    const float* __restrict__ We2, const float* __restrict__ ae2,
    unsigned int* __restrict__ meta_pay, int* __restrict__ counts, int E) {
    __shared__ float wvs[32];
    __shared__ int hist[NBUK];
    int tid = threadIdx.x, i = blockIdx.x;
    if (tid < 32) {
        const float* Wp = (tid < 16) ? We1 : We2;
        const float* ap = (tid < 16) ? ae1 : ae2;
        int f = tid & 15;
        float s = 0.f;
        for (int k = 0; k < 64; ++k) s += Wp[f * 64 + k] * ap[k];
        wvs[tid] = s;
    }
    for (int t = tid; t < NBUK; t += 256) hist[t] = 0;
    __syncthreads();
    int e0 = i * EPB, e1 = min(E, e0 + EPB);
    for (int e = e0 + tid; e < e1; e += 256) {
        int d = dst[e];
        atomicAdd(&hist[d >> 8], 1);
        const float4* ep = (const float4*)(eattr + (size_t)e * 16);
        float4 q0 = ep[0], q1 = ep[1], q2 = ep[2], q3 = ep[3];
        float a[16] = {q0.x, q0.y, q0.z, q0.w, q1.x, q1.y, q1.z, q1.w,
                       q2.x, q2.y, q2.z, q2.w, q3.x, q3.y, q3.z, q3.w};
        float s1 = 0.f, s2 = 0.f;
#pragma unroll
        for (int f = 0; f < 16; ++f) { s1 += a[f] * wvs[f]; s2 += a[f] * wvs[16 + f]; }
        unsigned int p1 = (unsigned int)__half_as_ushort(__float2half_rn(s1));
        unsigned int p2 = (unsigned int)__half_as_ushort(__float2half_rn(s2));
        meta_pay[e] = p1 | (p2 << 16);
    }
    __syncthreads();
    for (int t = tid; t < NBUK; t += 256) counts[(size_t)i * NBUK + t] = hist[t];
}

// ---------------- K2a: per-bucket exclusive scan over blocks ----------------
__global__ __launch_bounds__(1024) void scan_cols(const int* __restrict__ counts,
                                                  int* __restrict__ offsets,
                                                  int* __restrict__ btot, int nblk) {
    __shared__ int sh[1024];
    int b = blockIdx.x, t = threadIdx.x;
    int v = (t < nblk) ? counts[(size_t)t * NBUK + b] : 0;
    sh[t] = v;
    __syncthreads();
    for (int off = 1; off < 1024; off <<= 1) {
        int u = (t >= off) ? sh[t - off] : 0;
        __syncthreads();
        sh[t] += u;
        __syncthreads();
    }
    if (t < nblk) offsets[(size_t)t * NBUK + b] = sh[t] - v;
    if (t == 1023) btot[b] = sh[1023];
}

// ---------------- K2b: exclusive scan of 512 bucket totals -> bucket bases ----------------
__global__ void scan_buckets(const int* __restrict__ btot, int* __restrict__ bbase,
                             int* __restrict__ rowptr, int E, int n) {
    __shared__ int sh[NBUK];
    int t = threadIdx.x;
    int v = btot[t];
    sh[t] = v;
    __syncthreads();
    for (int off = 1; off < NBUK; off <<= 1) {
        int u = (t >= off) ? sh[t - off] : 0;
        __syncthreads();
        sh[t] += u;
        __syncthreads();
    }
    bbase[t] = sh[t] - v;
    if (t == 0) rowptr[n] = E;
}

// ---------------- K3: scatter edges into dst-bucketed array (LDS cursors only) ----------------
__global__ __launch_bounds__(256) void scatter_buckets(
    const int* __restrict__ dst, const int* __restrict__ src,
    const unsigned int* __restrict__ meta_pay, const int* __restrict__ offsets,
    const int* __restrict__ bbase, uint2* __restrict__ bucketed, int E) {
    __shared__ int cur[NBUK];
    int i = blockIdx.x, tid = threadIdx.x;
    for (int t = tid; t < NBUK; t += 256) cur[t] = bbase[t] + offsets[(size_t)i * NBUK + t];
    __syncthreads();
    int e0 = i * EPB, e1 = min(E, e0 + EPB);
    for (int e = e0 + tid; e < e1; e += 256) {
        int d = dst[e];
        int slot = atomicAdd(&cur[d >> 8], 1);
        bucketed[slot] = make_uint2((unsigned int)src[e] | ((unsigned int)(d & 255) << 24),
                                    meta_pay[e]);
    }
}

// ---------------- K4: per-bucket degree count + LDS scan -> rowptr + final CSR recs ----------------
__global__ __launch_bounds__(256) void csr_build(const uint2* __restrict__ bucketed,
                                                 const int* __restrict__ bbase,
                                                 const int* __restrict__ btot,
                                                 int* __restrict__ rowptr,
                                                 uint2* __restrict__ recs, int n) {
    __shared__ int deg[256], sc[256], cur[256];
    int b = blockIdx.x, tid = threadIdx.x;
    int base = bbase[b], cnt = btot[b];
    deg[tid] = 0;
    __syncthreads();
    for (int k = tid; k < cnt; k += 256) {
        uint2 r = bucketed[base + k];
        atomicAdd(&deg[r.x >> 24], 1);
    }
    __syncthreads();
    int dv = deg[tid];
    sc[tid] = dv;
    __syncthreads();
    for (int off = 1; off < 256; off <<= 1) {
        int u = (tid >= off) ? sc[tid - off] : 0;
        __syncthreads();
        sc[tid] += u;
        __syncthreads();
    }
    int excl = sc[tid] - dv;
    int d = b * 256 + tid;
    if (d < n) rowptr[d] = base + excl;
    cur[tid] = base + excl;
    __syncthreads();
    for (int k = tid; k < cnt; k += 256) {
        uint2 r = bucketed[base + k];
        int dl = (int)(r.x >> 24);
        int pos = atomicAdd(&cur[dl], 1);
        recs[pos] = make_uint2(r.x & 0x00FFFFFFu, r.y);
    }
}

// ---------------- node GEMM: h = X@W (K x 64) -> f16 rows, plus ash/adh (f32) ----------------
template <int K>
__global__ __launch_bounds__(256) void gemm_node(const float* __restrict__ X,
                                                 const float* __restrict__ W,
                                                 const float* __restrict__ a_s,
                                                 const float* __restrict__ a_d,
                                                 __half* __restrict__ Hout16,
                                                 float* __restrict__ ash,
                                                 float* __restrict__ adh, int n) {
    constexpr int KC = 64;
    __shared__ float xs[128 * 65];
    __shared__ float ws[KC * 64];
    int tid = threadIdx.x;
    int base = blockIdx.x * 128;
    int ct = tid & 7;
    int rt = tid >> 3;

    float acc[4][8];
#pragma unroll
    for (int i = 0; i < 4; ++i)
#pragma unroll
        for (int j = 0; j < 8; ++j) acc[i][j] = 0.f;

    for (int kc = 0; kc < K; kc += KC) {
#pragma unroll
        for (int p = 0; p < 8; ++p) {
            int idx = p * 256 + tid;
            int row = idx >> 4;
            int f4 = idx & 15;
            float4 q = make_float4(0.f, 0.f, 0.f, 0.f);
            if (base + row < n) q = *(const float4*)(X + (size_t)(base + row) * K + kc + f4 * 4);
            float* dp = xs + row * 65 + f4 * 4;
            dp[0] = q.x; dp[1] = q.y; dp[2] = q.z; dp[3] = q.w;
        }
#pragma unroll
        for (int p = 0; p < 4; ++p) {
            int idx = p * 256 + tid;
            int f = idx >> 4;
            int c4 = idx & 15;
            *(float4*)(ws + f * 64 + c4 * 4) =
                *(const float4*)(W + (size_t)(kc + f) * 64 + c4 * 4);
        }
        __syncthreads();
#pragma unroll 4
        for (int f = 0; f < KC; ++f) {
            float4 w0 = *(const float4*)(ws + f * 64 + ct * 8);
            float4 w1 = *(const float4*)(ws + f * 64 + ct * 8 + 4);
            float b0[8] = {w0.x, w0.y, w0.z, w0.w, w1.x, w1.y, w1.z, w1.w};
#pragma unroll
            for (int i = 0; i < 4; ++i) {
                float a = xs[(rt * 4 + i) * 65 + f];
#pragma unroll
                for (int j = 0; j < 8; ++j) acc[i][j] = fmaf(a, b0[j], acc[i][j]);
            }
        }
        __syncthreads();
    }

    float as_r[8], ad_r[8];
#pragma unroll
    for (int j = 0; j < 8; ++j) { as_r[j] = a_s[ct * 8 + j]; ad_r[j] = a_d[ct * 8 + j]; }
#pragma unroll
    for (int i = 0; i < 4; ++i) {
        int r = base + rt * 4 + i;
        float ps = 0.f, pd = 0.f;
#pragma unroll
        for (int j = 0; j < 8; ++j) {
            ps = fmaf(acc[i][j], as_r[j], ps);
            pd = fmaf(acc[i][j], ad_r[j], pd);
        }
        ps += __shfl_xor(ps, 1); pd += __shfl_xor(pd, 1);
        ps += __shfl_xor(ps, 2); pd += __shfl_xor(pd, 2);
        ps += __shfl_xor(ps, 4); pd += __shfl_xor(pd, 4);
        if (r < n) {
            union { __half h[8]; uint4 u; } pk;
#pragma unroll
            for (int j = 0; j < 8; ++j) pk.h[j] = __float2half_rn(acc[i][j]);
            *(uint4*)(Hout16 + (size_t)r * 64 + ct * 8) = pk.u;
            if (ct == 0) { ash[r] = ps; adh[r] = pd; }
        }
    }
}

// ---------------- GAT aggregation: one wave per destination node, 4 edges/iteration ----------------
// phase 1: lane l computes exp/byte-offset for edge c+l (lanes >= cnt pad with p=0,o=0),
//          stages 64 (o,p) pairs into wave-private LDS (no barrier: single-wave region).
// phase 2: wave splits as g=lane>>4 (edge in quad) x f4=lane&15 (feature quad). Per quad:
//          1 ds_read_b64 (broadcast per 16 lanes) + 1 global_load_dwordx2 fetches FOUR
//          full 128B rows per wave; 4 fma per lane. 4x fewer VMEM ops, ~2x fewer VALU ops.
template <int LAYER>
__global__ __launch_bounds__(256) void gat_aggregate(
    const __half* __restrict__ Hf, const float* __restrict__ ash, const float* __restrict__ adh,
    const int* __restrict__ rowptr, const uint2* __restrict__ recs,
    const float* __restrict__ bias, float* __restrict__ outp, int n) {
    __shared__ uint2 ops[4][64];
    int wave = threadIdx.x >> 6;
    int lane = threadIdx.x & 63;
    int i = blockIdx.x * 4 + wave;
    if (i >= n) return;
    int start = rowptr[i], end = rowptr[i + 1];
    float adi = adh[i];
    const char* Hb = (const char*)Hf;
    int g = lane >> 4;                    // edge slot within quad
    unsigned int fb = (unsigned int)((lane & 15) * 8);  // feature byte offset in row

    float acc0 = 0.f, acc1 = 0.f, acc2 = 0.f, acc3 = 0.f;
    float zl = 0.f, seal = 0.f;

    for (int c = start; c < end; c += 64) {
        int cnt = min(64, end - c);
        unsigned int o_l = 0;
        float p_l = 0.f;
        if (lane < cnt) {
            uint2 r = recs[c + lane];
            int s_l = (int)r.x;
            o_l = (unsigned int)s_l << 7;
            unsigned short u = (LAYER == 0) ? (unsigned short)(r.y & 0xffffu)
                                            : (unsigned short)(r.y >> 16);
            float e = __half2float(__ushort_as_half(u));
            float p = __expf(leaky(ash[s_l] + adi + e));
            p_l = p;
            zl += p;
            seal += e;
        }
        ops[wave][lane] = make_uint2(o_l, __float_as_uint(p_l));
        int nq = (cnt + 3) >> 2;
#pragma unroll 4
        for (int q = 0; q < nq; ++q) {
            uint2 op = ops[wave][q * 4 + g];
            uint2 hv = *(const uint2*)(Hb + (op.x + fb));
            float p = __uint_as_float(op.y);
            __half2 h01 = *(__half2*)&hv.x;
            __half2 h23 = *(__half2*)&hv.y;
            acc0 = fmaf(p, __half2float(h01.x), acc0);
            acc1 = fmaf(p, __half2float(h01.y), acc1);
            acc2 = fmaf(p, __half2float(h23.x), acc2);
            acc3 = fmaf(p, __half2float(h23.y), acc3);
        }
    }

    // reduce partial acc across the 4 edge slots (xor 16, 32); preserves lane&15 class
    acc0 += __shfl_xor(acc0, 16); acc1 += __shfl_xor(acc1, 16);
    acc2 += __shfl_xor(acc2, 16); acc3 += __shfl_xor(acc3, 16);
    acc0 += __shfl_xor(acc0, 32); acc1 += __shfl_xor(acc1, 32);
    acc2 += __shfl_xor(acc2, 32); acc3 += __shfl_xor(acc3, 32);

    float z = zl, sea = seal;
#pragma unroll
    for (int off = 1; off < 64; off <<= 1) {
        z += __shfl_xor(z, off);
        sea += __shfl_xor(sea, off);
    }

    int d = end - start;
    float loop_sc = sea / (float)max(d, 1);
    float aself = leaky(ash[i] + adi + loop_sc);
    float pself = __expf(aself);
    z += pself;

    // self row contribution for this lane's 4 features
    uint2 hvs = *(const uint2*)(Hb + (((size_t)i << 7) + fb));
    __half2 s01 = *(__half2*)&hvs.x;
    __half2 s23 = *(__half2*)&hvs.y;
    acc0 = fmaf(pself, __half2float(s01.x), acc0);
    acc1 = fmaf(pself, __half2float(s01.y), acc1);
    acc2 = fmaf(pself, __half2float(s23.x), acc2);
    acc3 = fmaf(pself, __half2float(s23.y), acc3);

    if (lane < 16) {
        float4 bv = *(const float4*)(bias + lane * 4);
        float4 o;
        o.x = fmaxf(acc0 / z + bv.x, 0.f);
        o.y = fmaxf(acc1 / z + bv.y, 0.f);
        o.z = fmaxf(acc2 / z + bv.z, 0.f);
        o.w = fmaxf(acc3 / z + bv.w, 0.f);
        *(float4*)(outp + (size_t)i * 64 + lane * 4) = o;
    }
}

// ---------------- classifier MLP: relu(X@Wc1+bc1)@Wc2+bc2 ----------------
__global__ __launch_bounds__(256) void mlp_kernel(const float* __restrict__ X,
                                                  const float* __restrict__ Wc1,
                                                  const float* __restrict__ bc1,
                                                  const float* __restrict__ Wc2,
                                                  const float* __restrict__ bc2,
                                                  float* __restrict__ outp, int n) {
    __shared__ float v[8 * 64];
    __shared__ float tb[8 * 32];
    int base = blockIdx.x * 8;
    for (int t = threadIdx.x; t < 512; t += 256) {
        int r = t >> 6;
        v[t] = (base + r < n) ? X[(size_t)base * 64 + t] : 0.f;
    }
    __syncthreads();
    int r = threadIdx.x >> 5, j = threadIdx.x & 31;
    float acc = bc1[j];
#pragma unroll
    for (int k = 0; k < 64; ++k) acc += v[r * 64 + k] * Wc1[k * 32 + j];
    acc = fmaxf(acc, 0.f);
    tb[r * 32 + j] = acc;
    __syncthreads();
    float lg = bc2[j];
#pragma unroll
    for (int k2 = 0; k2 < 32; ++k2) lg += tb[r * 32 + k2] * Wc2[k2 * 32 + j];
    int row = base + r;
    if (row < n) outp[(size_t)row * 32 + j] = lg;
}

extern "C" void kernel_launch(void* const* d_in, const int* in_sizes, int n_in,
                              void* d_out, int out_size, void* d_ws, size_t ws_size,
                              hipStream_t stream) {
    const float* x    = (const float*)d_in[0];
    const int*   ei   = (const int*)d_in[1];
    const float* eatt = (const float*)d_in[2];
    const float* W1   = (const float*)d_in[3];
    const float* as1  = (const float*)d_in[4];
    const float* ad1  = (const float*)d_in[5];
    const float* We1  = (const float*)d_in[6];
    const float* ae1  = (const float*)d_in[7];
    const float* b1   = (const float*)d_in[8];
    const float* W2   = (const float*)d_in[9];
    const float* as2  = (const float*)d_in[10];
    const float* ad2  = (const float*)d_in[11];
    const float* We2  = (const float*)d_in[12];
    const float* ae2  = (const float*)d_in[13];
    const float* b2   = (const float*)d_in[14];
    const float* Wc1  = (const float*)d_in[15];
    const float* bc1  = (const float*)d_in[16];
    const float* Wc2  = (const float*)d_in[17];
    const float* bc2  = (const float*)d_in[18];

    int n = in_sizes[0] / 128;
    int E = in_sizes[1] / 2;
    const int* src = ei;
    const int* dst = ei + E;
    int nblk = (E + EPB - 1) / EPB;  // must be <= 1024 (E <= 2.09M)

    // workspace carve (256B aligned)
    char* w = (char*)d_ws;
    auto alloc = [&](size_t bytes) { void* p = (void*)w; w += (bytes + 255) & ~(size_t)255; return p; };
    int* rowptr   = (int*)alloc((size_t)(n + 1) * 4);
    int* counts   = (int*)alloc((size_t)nblk * NBUK * 4);
    int* offsets  = (int*)alloc((size_t)nblk * NBUK * 4);
    int* btot     = (int*)alloc((size_t)NBUK * 4);
    int* bbase    = (int*)alloc((size_t)NBUK * 4);
    unsigned int* meta_pay = (unsigned int*)alloc((size_t)E * 4);
    uint2* recs   = (uint2*)alloc((size_t)E * 8);
    __half* hbuf16 = (__half*)alloc((size_t)n * 64 * 2);
    float* obuf   = (float*)alloc((size_t)n * 64 * 4);
    float* ash    = (float*)alloc((size_t)n * 4);
    float* adh    = (float*)alloc((size_t)n * 4);
    // bucketed edge array aliases obuf: it is dead before gat_aggregate<0> writes obuf
    // (E*8 = 12.8MB <= n*64*4 = 25.6MB)
    uint2* bucketed = (uint2*)obuf;

    // ---- CSR build: no global returning atomics anywhere ----
    count_pack<<<nblk, 256, 0, stream>>>(dst, eatt, We1, ae1, We2, ae2, meta_pay, counts, E);
    scan_cols<<<NBUK, 1024, 0, stream>>>(counts, offsets, btot, nblk);
    scan_buckets<<<1, NBUK, 0, stream>>>(btot, bbase, rowptr, E, n);
    scatter_buckets<<<nblk, 256, 0, stream>>>(dst, src, meta_pay, offsets, bbase, bucketed, E);
    csr_build<<<NBUK, 256, 0, stream>>>(bucketed, bbase, btot, rowptr, recs, n);

    // layer 1
    gemm_node<128><<<(n + 127) / 128, 256, 0, stream>>>(x, W1, as1, ad1, hbuf16, ash, adh, n);
    gat_aggregate<0><<<(n + 3) / 4, 256, 0, stream>>>(hbuf16, ash, adh, rowptr, recs, b1, obuf, n);
    // layer 2
    gemm_node<64><<<(n + 127) / 128, 256, 0, stream>>>(obuf, W2, as2, ad2, hbuf16, ash, adh, n);
    gat_aggregate<1><<<(n + 3) / 4, 256, 0, stream>>>(hbuf16, ash, adh, rowptr, recs, b2, obuf, n);
    // classifier
    mlp_kernel<<<(n + 7) / 8, 256, 0, stream>>>(obuf, Wc1, bc1, Wc2, bc2, (float*)d_out, n);
}

// Round 7
// 464.448 us; speedup vs baseline: 1.1440x; 1.0281x over previous
//
#include <hip/hip_runtime.h>
#include <hip/hip_bf16.h>
#include <hip/hip_fp16.h>

#define NEG_SLOPE 0.2f
// CSR build geometry: 512 dst-buckets of 256 nodes (assumes n <= 131072),
// 2048 edges per counting block (assumes E <= 2048*1024 = 2.09M blocks-wise).
#define EPB 2048
#define NBUK 512

__device__ __forceinline__ float leaky(float a) { return a > 0.f ? a : NEG_SLOPE * a; }

// ---------------- K1: per-block bucket histogram + edge payload (f16|f16) ----------------
__global__ __launch_bounds__(256) void count_pack(
    const int* __restrict__ dst, const float* __restrict__ eattr,
    const float* __restrict__ We1, const float* __restrict__ ae1,
    const float* __restrict__ We2, const float* __restrict__ ae2,
    unsigned int* __restrict__ meta_pay, int* __restrict__ counts, int E) {
    __shared__ float wvs[32];
    __shared__ int hist[NBUK];
    int tid = threadIdx.x, i = blockIdx.x;
    if (tid < 32) {
        const float* Wp = (tid < 16) ? We1 : We2;
        const float* ap = (tid < 16) ? ae1 : ae2;
        int f = tid & 15;
        float s = 0.f;
        for (int k = 0; k < 64; ++k) s += Wp[f * 64 + k] * ap[k];
        wvs[tid] = s;
    }
    for (int t = tid; t < NBUK; t += 256) hist[t] = 0;
    __syncthreads();
    int e0 = i * EPB, e1 = min(E, e0 + EPB);
    for (int e = e0 + tid; e < e1; e += 256) {
        int d = dst[e];
        atomicAdd(&hist[d >> 8], 1);
        const float4* ep = (const float4*)(eattr + (size_t)e * 16);
        float4 q0 = ep[0], q1 = ep[1], q2 = ep[2], q3 = ep[3];
        float a[16] = {q0.x, q0.y, q0.z, q0.w, q1.x, q1.y, q1.z, q1.w,
                       q2.x, q2.y, q2.z, q2.w, q3.x, q3.y, q3.z, q3.w};
        float s1 = 0.f, s2 = 0.f;
#pragma unroll
        for (int f = 0; f < 16; ++f) { s1 += a[f] * wvs[f]; s2 += a[f] * wvs[16 + f]; }
        unsigned int p1 = (unsigned int)__half_as_ushort(__float2half_rn(s1));
        unsigned int p2 = (unsigned int)__half_as_ushort(__float2half_rn(s2));
        meta_pay[e] = p1 | (p2 << 16);
    }
    __syncthreads();
    for (int t = tid; t < NBUK; t += 256) counts[(size_t)i * NBUK + t] = hist[t];
}

// ---------------- K2a: per-bucket exclusive scan over blocks ----------------
__global__ __launch_bounds__(1024) void scan_cols(const int* __restrict__ counts,
                                                  int* __restrict__ offsets,
                                                  int* __restrict__ btot, int nblk) {
    __shared__ int sh[1024];
    int b = blockIdx.x, t = threadIdx.x;
    int v = (t < nblk) ? counts[(size_t)t * NBUK + b] : 0;
    sh[t] = v;
    __syncthreads();
    for (int off = 1; off < 1024; off <<= 1) {
        int u = (t >= off) ? sh[t - off] : 0;
        __syncthreads();
        sh[t] += u;
        __syncthreads();
    }
    if (t < nblk) offsets[(size_t)t * NBUK + b] = sh[t] - v;
    if (t == 1023) btot[b] = sh[1023];
}

// ---------------- K2b: exclusive scan of 512 bucket totals -> bucket bases ----------------
__global__ void scan_buckets(const int* __restrict__ btot, int* __restrict__ bbase,
                             int* __restrict__ rowptr, int E, int n) {
    __shared__ int sh[NBUK];
    int t = threadIdx.x;
    int v = btot[t];
    sh[t] = v;
    __syncthreads();
    for (int off = 1; off < NBUK; off <<= 1) {
        int u = (t >= off) ? sh[t - off] : 0;
        __syncthreads();
        sh[t] += u;
        __syncthreads();
    }
    bbase[t] = sh[t] - v;
    if (t == 0) rowptr[n] = E;
}

// ---------------- K3: scatter edges into dst-bucketed array (LDS cursors only) ----------------
__global__ __launch_bounds__(256) void scatter_buckets(
    const int* __restrict__ dst, const int* __restrict__ src,
    const unsigned int* __restrict__ meta_pay, const int* __restrict__ offsets,
    const int* __restrict__ bbase, uint2* __restrict__ bucketed, int E) {
    __shared__ int cur[NBUK];
    int i = blockIdx.x, tid = threadIdx.x;
    for (int t = tid; t < NBUK; t += 256) cur[t] = bbase[t] + offsets[(size_t)i * NBUK + t];
    __syncthreads();
    int e0 = i * EPB, e1 = min(E, e0 + EPB);
    for (int e = e0 + tid; e < e1; e += 256) {
        int d = dst[e];
        int slot = atomicAdd(&cur[d >> 8], 1);
        bucketed[slot] = make_uint2((unsigned int)src[e] | ((unsigned int)(d & 255) << 24),
                                    meta_pay[e]);
    }
}

// ---------------- K4: per-bucket degree count + LDS scan -> rowptr + final CSR recs ----------------
__global__ __launch_bounds__(256) void csr_build(const uint2* __restrict__ bucketed,
                                                 const int* __restrict__ bbase,
                                                 const int* __restrict__ btot,
                                                 int* __restrict__ rowptr,
                                                 uint2* __restrict__ recs, int n) {
    __shared__ int deg[256], sc[256], cur[256];
    int b = blockIdx.x, tid = threadIdx.x;
    int base = bbase[b], cnt = btot[b];
    deg[tid] = 0;
    __syncthreads();
    for (int k = tid; k < cnt; k += 256) {
        uint2 r = bucketed[base + k];
        atomicAdd(&deg[r.x >> 24], 1);
    }
    __syncthreads();
    int dv = deg[tid];
    sc[tid] = dv;
    __syncthreads();
    for (int off = 1; off < 256; off <<= 1) {
        int u = (tid >= off) ? sc[tid - off] : 0;
        __syncthreads();
        sc[tid] += u;
        __syncthreads();
    }
    int excl = sc[tid] - dv;
    int d = b * 256 + tid;
    if (d < n) rowptr[d] = base + excl;
    cur[tid] = base + excl;
    __syncthreads();
    for (int k = tid; k < cnt; k += 256) {
        uint2 r = bucketed[base + k];
        int dl = (int)(r.x >> 24);
        int pos = atomicAdd(&cur[dl], 1);
        recs[pos] = make_uint2(r.x & 0x00FFFFFFu, r.y);
    }
}

// ---------------- node GEMM: h = X@W (K x 64) -> f16 rows, plus ash/adh (f32) ----------------
template <int K>
__global__ __launch_bounds__(256) void gemm_node(const float* __restrict__ X,
                                                 const float* __restrict__ W,
                                                 const float* __restrict__ a_s,
                                                 const float* __restrict__ a_d,
                                                 __half* __restrict__ Hout16,
                                                 float* __restrict__ ash,
                                                 float* __restrict__ adh, int n) {
    constexpr int KC = 64;
    __shared__ float xs[128 * 65];
    __shared__ float ws[KC * 64];
    int tid = threadIdx.x;
    int base = blockIdx.x * 128;
    int ct = tid & 7;
    int rt = tid >> 3;

    float acc[4][8];
#pragma unroll
    for (int i = 0; i < 4; ++i)
#pragma unroll
        for (int j = 0; j < 8; ++j) acc[i][j] = 0.f;

    for (int kc = 0; kc < K; kc += KC) {
#pragma unroll
        for (int p = 0; p < 8; ++p) {
            int idx = p * 256 + tid;
            int row = idx >> 4;
            int f4 = idx & 15;
            float4 q = make_float4(0.f, 0.f, 0.f, 0.f);
            if (base + row < n) q = *(const float4*)(X + (size_t)(base + row) * K + kc + f4 * 4);
            float* dp = xs + row * 65 + f4 * 4;
            dp[0] = q.x; dp[1] = q.y; dp[2] = q.z; dp[3] = q.w;
        }
#pragma unroll
        for (int p = 0; p < 4; ++p) {
            int idx = p * 256 + tid;
            int f = idx >> 4;
            int c4 = idx & 15;
            *(float4*)(ws + f * 64 + c4 * 4) =
                *(const float4*)(W + (size_t)(kc + f) * 64 + c4 * 4);
        }
        __syncthreads();
#pragma unroll 4
        for (int f = 0; f < KC; ++f) {
            float4 w0 = *(const float4*)(ws + f * 64 + ct * 8);
            float4 w1 = *(const float4*)(ws + f * 64 + ct * 8 + 4);
            float b0[8] = {w0.x, w0.y, w0.z, w0.w, w1.x, w1.y, w1.z, w1.w};
#pragma unroll
            for (int i = 0; i < 4; ++i) {
                float a = xs[(rt * 4 + i) * 65 + f];
#pragma unroll
                for (int j = 0; j < 8; ++j) acc[i][j] = fmaf(a, b0[j], acc[i][j]);
            }
        }
        __syncthreads();
    }

    float as_r[8], ad_r[8];
#pragma unroll
    for (int j = 0; j < 8; ++j) { as_r[j] = a_s[ct * 8 + j]; ad_r[j] = a_d[ct * 8 + j]; }
#pragma unroll
    for (int i = 0; i < 4; ++i) {
        int r = base + rt * 4 + i;
        float ps = 0.f, pd = 0.f;
#pragma unroll
        for (int j = 0; j < 8; ++j) {
            ps = fmaf(acc[i][j], as_r[j], ps);
            pd = fmaf(acc[i][j], ad_r[j], pd);
        }
        ps += __shfl_xor(ps, 1); pd += __shfl_xor(pd, 1);
        ps += __shfl_xor(ps, 2); pd += __shfl_xor(pd, 2);
        ps += __shfl_xor(ps, 4); pd += __shfl_xor(pd, 4);
        if (r < n) {
            union { __half h[8]; uint4 u; } pk;
#pragma unroll
            for (int j = 0; j < 8; ++j) pk.h[j] = __float2half_rn(acc[i][j]);
            *(uint4*)(Hout16 + (size_t)r * 64 + ct * 8) = pk.u;
            if (ct == 0) { ash[r] = ps; adh[r] = pd; }
        }
    }
}

// ---------------- GAT aggregation: FOUR nodes per wave (16-lane groups) ----------------
// avg degree = E/N ~ 16, so a 16-lane group matches a node's typical edge count.
// gr = lane>>4 selects the node slot; fl = lane&15 is both edge slot (phase 1) and
// feature-quad slot (phase 2). The 4 consecutive nodes' CSR ranges are contiguous ->
// the wave's 64 recs loads are one nearly-contiguous region; the 4 per-node chains
// run in lockstep for 4x latency hiding. Per loop iteration, one wave-wide VMEM
// fetches 4 full 128B rows (one per group).
template <int LAYER>
__global__ __launch_bounds__(256) void gat_aggregate(
    const __half* __restrict__ Hf, const float* __restrict__ ash, const float* __restrict__ adh,
    const int* __restrict__ rowptr, const uint2* __restrict__ recs,
    const float* __restrict__ bias, float* __restrict__ outp, int n) {
    __shared__ uint2 ops[4][4 * 17];  // [wave][group*17 + k], stride 17 spreads banks
    int wave = threadIdx.x >> 6;
    int lane = threadIdx.x & 63;
    int gr = lane >> 4;
    int fl = lane & 15;
    int i = blockIdx.x * 16 + wave * 4 + gr;
    if (i >= n) return;
    int start = rowptr[i], end = rowptr[i + 1];
    float adi = adh[i];
    const char* Hb = (const char*)Hf;
    unsigned int fb = (unsigned int)(fl * 8);

    float acc0 = 0.f, acc1 = 0.f, acc2 = 0.f, acc3 = 0.f;
    float zl = 0.f, seal = 0.f;

    for (int c = start; c < end; c += 16) {
        int cnt = min(16, end - c);
        unsigned int o_l = 0;
        float p_l = 0.f;
        if (fl < cnt) {
            uint2 r = recs[c + fl];
            int s_l = (int)r.x;
            o_l = (unsigned int)s_l << 7;
            unsigned short u = (LAYER == 0) ? (unsigned short)(r.y & 0xffffu)
                                            : (unsigned short)(r.y >> 16);
            float e = __half2float(__ushort_as_half(u));
            float p = __expf(leaky(ash[s_l] + adi + e));
            p_l = p;
            zl += p;
            seal += e;
        }
        ops[wave][gr * 17 + fl] = make_uint2(o_l, __float_as_uint(p_l));
        // same-wave LDS dependency; compiler inserts lgkmcnt wait, no barrier needed
        for (int k = 0; k < cnt; ++k) {
            uint2 op = ops[wave][gr * 17 + k];  // group-uniform -> LDS broadcast
            uint2 hv = *(const uint2*)(Hb + (op.x + fb));
            float p = __uint_as_float(op.y);
            __half2 h01 = *(__half2*)&hv.x;
            __half2 h23 = *(__half2*)&hv.y;
            acc0 = fmaf(p, __half2float(h01.x), acc0);
            acc1 = fmaf(p, __half2float(h01.y), acc1);
            acc2 = fmaf(p, __half2float(h23.x), acc2);
            acc3 = fmaf(p, __half2float(h23.y), acc3);
        }
    }

    // reduce z / sea within the 16-lane group (4 butterfly rounds)
#pragma unroll
    for (int off = 1; off < 16; off <<= 1) {
        zl += __shfl_xor(zl, off);
        seal += __shfl_xor(seal, off);
    }

    int d = end - start;
    float loop_sc = seal / (float)max(d, 1);
    float aself = leaky(ash[i] + adi + loop_sc);
    float pself = __expf(aself);
    float z = zl + pself;

    // self row contribution for this lane's 4 features
    uint2 hvs = *(const uint2*)(Hb + (((unsigned int)i << 7) + fb));
    __half2 s01 = *(__half2*)&hvs.x;
    __half2 s23 = *(__half2*)&hvs.y;
    acc0 = fmaf(pself, __half2float(s01.x), acc0);
    acc1 = fmaf(pself, __half2float(s01.y), acc1);
    acc2 = fmaf(pself, __half2float(s23.x), acc2);
    acc3 = fmaf(pself, __half2float(s23.y), acc3);

    float4 bv = *(const float4*)(bias + fl * 4);
    float4 o;
    o.x = fmaxf(acc0 / z + bv.x, 0.f);
    o.y = fmaxf(acc1 / z + bv.y, 0.f);
    o.z = fmaxf(acc2 / z + bv.z, 0.f);
    o.w = fmaxf(acc3 / z + bv.w, 0.f);
    *(float4*)(outp + (size_t)i * 64 + fl * 4) = o;
}

// ---------------- classifier MLP: relu(X@Wc1+bc1)@Wc2+bc2 ----------------
__global__ __launch_bounds__(256) void mlp_kernel(const float* __restrict__ X,
                                                  const float* __restrict__ Wc1,
                                                  const float* __restrict__ bc1,
                                                  const float* __restrict__ Wc2,
                                                  const float* __restrict__ bc2,
                                                  float* __restrict__ outp, int n) {
    __shared__ float v[8 * 64];
    __shared__ float tb[8 * 32];
    int base = blockIdx.x * 8;
    for (int t = threadIdx.x; t < 512; t += 256) {
        int r = t >> 6;
        v[t] = (base + r < n) ? X[(size_t)base * 64 + t] : 0.f;
    }
    __syncthreads();
    int r = threadIdx.x >> 5, j = threadIdx.x & 31;
    float acc = bc1[j];
#pragma unroll
    for (int k = 0; k < 64; ++k) acc += v[r * 64 + k] * Wc1[k * 32 + j];
    acc = fmaxf(acc, 0.f);
    tb[r * 32 + j] = acc;
    __syncthreads();
    float lg = bc2[j];
#pragma unroll
    for (int k2 = 0; k2 < 32; ++k2) lg += tb[r * 32 + k2] * Wc2[k2 * 32 + j];
    int row = base + r;
    if (row < n) outp[(size_t)row * 32 + j] = lg;
}

extern "C" void kernel_launch(void* const* d_in, const int* in_sizes, int n_in,
                              void* d_out, int out_size, void* d_ws, size_t ws_size,
                              hipStream_t stream) {
    const float* x    = (const float*)d_in[0];
    const int*   ei   = (const int*)d_in[1];
    const float* eatt = (const float*)d_in[2];
    const float* W1   = (const float*)d_in[3];
    const float* as1  = (const float*)d_in[4];
    const float* ad1  = (const float*)d_in[5];
    const float* We1  = (const float*)d_in[6];
    const float* ae1  = (const float*)d_in[7];
    const float* b1   = (const float*)d_in[8];
    const float* W2   = (const float*)d_in[9];
    const float* as2  = (const float*)d_in[10];
    const float* ad2  = (const float*)d_in[11];
    const float* We2  = (const float*)d_in[12];
    const float* ae2  = (const float*)d_in[13];
    const float* b2   = (const float*)d_in[14];
    const float* Wc1  = (const float*)d_in[15];
    const float* bc1  = (const float*)d_in[16];
    const float* Wc2  = (const float*)d_in[17];
    const float* bc2  = (const float*)d_in[18];

    int n = in_sizes[0] / 128;
    int E = in_sizes[1] / 2;
    const int* src = ei;
    const int* dst = ei + E;
    int nblk = (E + EPB - 1) / EPB;  // must be <= 1024 (E <= 2.09M)

    // workspace carve (256B aligned)
    char* w = (char*)d_ws;
    auto alloc = [&](size_t bytes) { void* p = (void*)w; w += (bytes + 255) & ~(size_t)255; return p; };
    int* rowptr   = (int*)alloc((size_t)(n + 1) * 4);
    int* counts   = (int*)alloc((size_t)nblk * NBUK * 4);
    int* offsets  = (int*)alloc((size_t)nblk * NBUK * 4);
    int* btot     = (int*)alloc((size_t)NBUK * 4);
    int* bbase    = (int*)alloc((size_t)NBUK * 4);
    unsigned int* meta_pay = (unsigned int*)alloc((size_t)E * 4);
    uint2* recs   = (uint2*)alloc((size_t)E * 8);
    __half* hbuf16 = (__half*)alloc((size_t)n * 64 * 2);
    float* obuf   = (float*)alloc((size_t)n * 64 * 4);
    float* ash    = (float*)alloc((size_t)n * 4);
    float* adh    = (float*)alloc((size_t)n * 4);
    // bucketed edge array aliases obuf: it is dead before gat_aggregate<0> writes obuf
    // (E*8 = 12.8MB <= n*64*4 = 25.6MB)
    uint2* bucketed = (uint2*)obuf;

    // ---- CSR build: no global returning atomics anywhere ----
    count_pack<<<nblk, 256, 0, stream>>>(dst, eatt, We1, ae1, We2, ae2, meta_pay, counts, E);
    scan_cols<<<NBUK, 1024, 0, stream>>>(counts, offsets, btot, nblk);
    scan_buckets<<<1, NBUK, 0, stream>>>(btot, bbase, rowptr, E, n);
    scatter_buckets<<<nblk, 256, 0, stream>>>(dst, src, meta_pay, offsets, bbase, bucketed, E);
    csr_build<<<NBUK, 256, 0, stream>>>(bucketed, bbase, btot, rowptr, recs, n);

    // layer 1
    gemm_node<128><<<(n + 127) / 128, 256, 0, stream>>>(x, W1, as1, ad1, hbuf16, ash, adh, n);
    gat_aggregate<0><<<(n + 15) / 16, 256, 0, stream>>>(hbuf16, ash, adh, rowptr, recs, b1, obuf, n);
    // layer 2
    gemm_node<64><<<(n + 127) / 128, 256, 0, stream>>>(obuf, W2, as2, ad2, hbuf16, ash, adh, n);
    gat_aggregate<1><<<(n + 15) / 16, 256, 0, stream>>>(hbuf16, ash, adh, rowptr, recs, b2, obuf, n);
    // classifier
    mlp_kernel<<<(n + 7) / 8, 256, 0, stream>>>(obuf, Wc1, bc1, Wc2, bc2, (float*)d_out, n);
}

// Round 8
// 433.681 us; speedup vs baseline: 1.2251x; 1.0709x over previous
//
#include <hip/hip_runtime.h>
#include <hip/hip_bf16.h>
#include <hip/hip_fp16.h>

#define NEG_SLOPE 0.2f
// CSR build geometry: 512 dst-buckets of 256 nodes (assumes n <= 131072),
// 2048 edges per counting block (assumes E <= 2048*1024 = 2.09M).
#define EPB 2048
#define NBUK 512

typedef _Float16 f16x8 __attribute__((ext_vector_type(8)));
typedef float f32x4 __attribute__((ext_vector_type(4)));

__device__ __forceinline__ float leaky(float a) { return a > 0.f ? a : NEG_SLOPE * a; }

// ---------------- K0: W transpose + f16 convert (Wt[c][k] = W[k][c]) ----------------
__global__ __launch_bounds__(256) void prep_w(const float* __restrict__ W1,
                                              const float* __restrict__ W2,
                                              __half* __restrict__ Wt1,
                                              __half* __restrict__ Wt2) {
    int t = threadIdx.x + blockIdx.x * 256;
    if (t < 8192) {
        int k = t >> 6, c = t & 63;
        Wt1[c * 128 + k] = __float2half_rn(W1[t]);
    } else if (t < 12288) {
        int i = t - 8192;
        int k = i >> 6, c = i & 63;
        Wt2[c * 64 + k] = __float2half_rn(W2[i]);
    }
}

// ---------------- K1: per-block bucket histogram + edge payload (f16|f16) ----------------
__global__ __launch_bounds__(256) void count_pack(
    const int* __restrict__ dst, const float* __restrict__ eattr,
    const float* __restrict__ We1, const float* __restrict__ ae1,
    const float* __restrict__ We2, const float* __restrict__ ae2,
    unsigned int* __restrict__ meta_pay, int* __restrict__ counts, int E) {
    __shared__ float wvs[32];
    __shared__ int hist[NBUK];
    int tid = threadIdx.x, i = blockIdx.x;
    if (tid < 32) {
        const float* Wp = (tid < 16) ? We1 : We2;
        const float* ap = (tid < 16) ? ae1 : ae2;
        int f = tid & 15;
        float s = 0.f;
        for (int k = 0; k < 64; ++k) s += Wp[f * 64 + k] * ap[k];
        wvs[tid] = s;
    }
    for (int t = tid; t < NBUK; t += 256) hist[t] = 0;
    __syncthreads();
    int e0 = i * EPB, e1 = min(E, e0 + EPB);
    for (int e = e0 + tid; e < e1; e += 256) {
        int d = dst[e];
        atomicAdd(&hist[d >> 8], 1);
        const float4* ep = (const float4*)(eattr + (size_t)e * 16);
        float4 q0 = ep[0], q1 = ep[1], q2 = ep[2], q3 = ep[3];
        float a[16] = {q0.x, q0.y, q0.z, q0.w, q1.x, q1.y, q1.z, q1.w,
                       q2.x, q2.y, q2.z, q2.w, q3.x, q3.y, q3.z, q3.w};
        float s1 = 0.f, s2 = 0.f;
#pragma unroll
        for (int f = 0; f < 16; ++f) { s1 += a[f] * wvs[f]; s2 += a[f] * wvs[16 + f]; }
        unsigned int p1 = (unsigned int)__half_as_ushort(__float2half_rn(s1));
        unsigned int p2 = (unsigned int)__half_as_ushort(__float2half_rn(s2));
        meta_pay[e] = p1 | (p2 << 16);
    }
    __syncthreads();
    for (int t = tid; t < NBUK; t += 256) counts[(size_t)i * NBUK + t] = hist[t];
}

// ---------------- K2a: per-bucket exclusive scan over blocks ----------------
__global__ __launch_bounds__(1024) void scan_cols(const int* __restrict__ counts,
                                                  int* __restrict__ offsets,
                                                  int* __restrict__ btot, int nblk) {
    __shared__ int sh[1024];
    int b = blockIdx.x, t = threadIdx.x;
    int v = (t < nblk) ? counts[(size_t)t * NBUK + b] : 0;
    sh[t] = v;
    __syncthreads();
    for (int off = 1; off < 1024; off <<= 1) {
        int u = (t >= off) ? sh[t - off] : 0;
        __syncthreads();
        sh[t] += u;
        __syncthreads();
    }
    if (t < nblk) offsets[(size_t)t * NBUK + b] = sh[t] - v;
    if (t == 1023) btot[b] = sh[1023];
}

// ---------------- K2b: exclusive scan of 512 bucket totals -> bucket bases ----------------
__global__ void scan_buckets(const int* __restrict__ btot, int* __restrict__ bbase,
                             int* __restrict__ rowptr, int E, int n) {
    __shared__ int sh[NBUK];
    int t = threadIdx.x;
    int v = btot[t];
    sh[t] = v;
    __syncthreads();
    for (int off = 1; off < NBUK; off <<= 1) {
        int u = (t >= off) ? sh[t - off] : 0;
        __syncthreads();
        sh[t] += u;
        __syncthreads();
    }
    bbase[t] = sh[t] - v;
    if (t == 0) rowptr[n] = E;
}

// ---------------- K3: scatter edges into dst-bucketed array (LDS cursors only) ----------------
__global__ __launch_bounds__(256) void scatter_buckets(
    const int* __restrict__ dst, const int* __restrict__ src,
    const unsigned int* __restrict__ meta_pay, const int* __restrict__ offsets,
    const int* __restrict__ bbase, uint2* __restrict__ bucketed, int E) {
    __shared__ int cur[NBUK];
    int i = blockIdx.x, tid = threadIdx.x;
    for (int t = tid; t < NBUK; t += 256) cur[t] = bbase[t] + offsets[(size_t)i * NBUK + t];
    __syncthreads();
    int e0 = i * EPB, e1 = min(E, e0 + EPB);
    for (int e = e0 + tid; e < e1; e += 256) {
        int d = dst[e];
        int slot = atomicAdd(&cur[d >> 8], 1);
        bucketed[slot] = make_uint2((unsigned int)src[e] | ((unsigned int)(d & 255) << 24),
                                    meta_pay[e]);
    }
}

// ---------------- K4: per-bucket degree count + LDS scan -> rowptr + final CSR recs ----------------
__global__ __launch_bounds__(256) void csr_build(const uint2* __restrict__ bucketed,
                                                 const int* __restrict__ bbase,
                                                 const int* __restrict__ btot,
                                                 int* __restrict__ rowptr,
                                                 uint2* __restrict__ recs, int n) {
    __shared__ int deg[256], sc[256], cur[256];
    int b = blockIdx.x, tid = threadIdx.x;
    int base = bbase[b], cnt = btot[b];
    deg[tid] = 0;
    __syncthreads();
    for (int k = tid; k < cnt; k += 256) {
        uint2 r = bucketed[base + k];
        atomicAdd(&deg[r.x >> 24], 1);
    }
    __syncthreads();
    int dv = deg[tid];
    sc[tid] = dv;
    __syncthreads();
    for (int off = 1; off < 256; off <<= 1) {
        int u = (tid >= off) ? sc[tid - off] : 0;
        __syncthreads();
        sc[tid] += u;
        __syncthreads();
    }
    int excl = sc[tid] - dv;
    int d = b * 256 + tid;
    if (d < n) rowptr[d] = base + excl;
    cur[tid] = base + excl;
    __syncthreads();
    for (int k = tid; k < cnt; k += 256) {
        uint2 r = bucketed[base + k];
        int dl = (int)(r.x >> 24);
        int pos = atomicAdd(&cur[dl], 1);
        recs[pos] = make_uint2(r.x & 0x00FFFFFFu, r.y);
    }
}

// ---------------- node GEMM via MFMA: h = X@W -> f16 rows + ash/adh ----------------
// LDS-free, barrier-free. Wave computes 16 nodes x 64 features. mfma(A=Wt frag, B=X frag):
// A row = lane&15 -> feature (within 16-tile), B col = lane&15 -> node;
// D: col = lane&15 = node, row = (lane>>4)*4+reg = feature (m89-verified layout).
// X fragments load direct from global (each element once, 64B segments) + in-reg f32->f16.
template <int K>
__global__ __launch_bounds__(256) void gemm_node_mfma(
    const float* __restrict__ X, const __half* __restrict__ Wt,
    const float* __restrict__ a_s, const float* __restrict__ a_d,
    __half* __restrict__ Hout16, float* __restrict__ ash, float* __restrict__ adh, int n) {
    int tid = threadIdx.x;
    int wave = tid >> 6, lane = tid & 63;
    int g = lane >> 4, q15 = lane & 15;
    int node = blockIdx.x * 64 + wave * 16 + q15;
    int nodec = min(node, n - 1);
    const float* xrow = X + (size_t)nodec * K + g * 8;
    const _Float16* wbase = (const _Float16*)Wt + (size_t)q15 * K + g * 8;

    f32x4 acc[4];
#pragma unroll
    for (int t = 0; t < 4; ++t) acc[t] = (f32x4){0.f, 0.f, 0.f, 0.f};

#pragma unroll
    for (int kk = 0; kk < K / 32; ++kk) {
        float4 xa = *(const float4*)(xrow + kk * 32);
        float4 xc = *(const float4*)(xrow + kk * 32 + 4);
        f16x8 xb;
        xb[0] = (_Float16)xa.x; xb[1] = (_Float16)xa.y;
        xb[2] = (_Float16)xa.z; xb[3] = (_Float16)xa.w;
        xb[4] = (_Float16)xc.x; xb[5] = (_Float16)xc.y;
        xb[6] = (_Float16)xc.z; xb[7] = (_Float16)xc.w;
#pragma unroll
        for (int t = 0; t < 4; ++t) {
            f16x8 wa = *(const f16x8*)(wbase + t * 16 * K + kk * 32);
            acc[t] = __builtin_amdgcn_mfma_f32_16x16x32_f16(wa, xb, acc[t], 0, 0, 0);
        }
    }

    float ps = 0.f, pd = 0.f;
#pragma unroll
    for (int t = 0; t < 4; ++t)
#pragma unroll
        for (int r = 0; r < 4; ++r) {
            int f = t * 16 + g * 4 + r;
            ps = fmaf(acc[t][r], a_s[f], ps);
            pd = fmaf(acc[t][r], a_d[f], pd);
        }
    ps += __shfl_xor(ps, 16); pd += __shfl_xor(pd, 16);
    ps += __shfl_xor(ps, 32); pd += __shfl_xor(pd, 32);

    if (node < n) {
#pragma unroll
        for (int t = 0; t < 4; ++t) {
            union { _Float16 h[4]; uint2 u2; } pk;
#pragma unroll
            for (int r = 0; r < 4; ++r) pk.h[r] = (_Float16)acc[t][r];
            *(uint2*)(Hout16 + (size_t)node * 64 + t * 16 + g * 4) = pk.u2;
        }
        if (g == 0) { ash[node] = ps; adh[node] = pd; }
    }
}

// ---------------- GAT aggregation: 4 nodes/wave; LAYER==1 fuses the classifier MLP ----------------
template <int LAYER>
__global__ __launch_bounds__(256) void gat_aggregate(
    const __half* __restrict__ Hf, const float* __restrict__ ash, const float* __restrict__ adh,
    const int* __restrict__ rowptr, const uint2* __restrict__ recs,
    const float* __restrict__ bias,
    const float* __restrict__ Wc1, const float* __restrict__ bc1,
    const float* __restrict__ Wc2, const float* __restrict__ bc2,
    float* __restrict__ outp, int n) {
    __shared__ uint2 ops[4][4 * 17];
    // LAYER==1: wc1s(2048) | wc2s(1024) | bc1|bc2 (64) | o rows (16*64) | t1 rows (16*32)
    __shared__ float mlpbuf[LAYER ? (2048 + 1024 + 64 + 1024 + 512) : 1];

    if (LAYER == 1) {
        for (int t = threadIdx.x; t < 2048; t += 256) mlpbuf[t] = Wc1[t];
        for (int t = threadIdx.x; t < 1024; t += 256) mlpbuf[2048 + t] = Wc2[t];
        if (threadIdx.x < 32) mlpbuf[3072 + threadIdx.x] = bc1[threadIdx.x];
        else if (threadIdx.x < 64) mlpbuf[3072 + threadIdx.x] = bc2[threadIdx.x - 32];
        __syncthreads();
    }

    int wave = threadIdx.x >> 6;
    int lane = threadIdx.x & 63;
    int gr = lane >> 4;
    int fl = lane & 15;
    int i = blockIdx.x * 16 + wave * 4 + gr;
    bool valid = i < n;
    int ic = valid ? i : 0;
    int start = 0, end = 0;
    if (valid) { start = rowptr[i]; end = rowptr[i + 1]; }
    float adi = adh[ic];
    const char* Hb = (const char*)Hf;
    unsigned int fb = (unsigned int)(fl * 8);

    float acc0 = 0.f, acc1 = 0.f, acc2 = 0.f, acc3 = 0.f;
    float zl = 0.f, seal = 0.f;

    for (int c = start; c < end; c += 16) {
        int cnt = min(16, end - c);
        unsigned int o_l = 0;
        float p_l = 0.f;
        if (fl < cnt) {
            uint2 r = recs[c + fl];
            int s_l = (int)r.x;
            o_l = (unsigned int)s_l << 7;
            unsigned short u = (LAYER == 0) ? (unsigned short)(r.y & 0xffffu)
                                            : (unsigned short)(r.y >> 16);
            float e = __half2float(__ushort_as_half(u));
            float p = __expf(leaky(ash[s_l] + adi + e));
            p_l = p;
            zl += p;
            seal += e;
        }
        ops[wave][gr * 17 + fl] = make_uint2(o_l, __float_as_uint(p_l));
        // same-wave LDS dependency; lgkmcnt ordering, no barrier needed
        for (int k = 0; k < cnt; ++k) {
            uint2 op = ops[wave][gr * 17 + k];  // group-uniform -> LDS broadcast
            uint2 hv = *(const uint2*)(Hb + (op.x + fb));
            float p = __uint_as_float(op.y);
            __half2 h01 = *(__half2*)&hv.x;
            __half2 h23 = *(__half2*)&hv.y;
            acc0 = fmaf(p, __half2float(h01.x), acc0);
            acc1 = fmaf(p, __half2float(h01.y), acc1);
            acc2 = fmaf(p, __half2float(h23.x), acc2);
            acc3 = fmaf(p, __half2float(h23.y), acc3);
        }
    }

    if (valid) {
        // reduce z / sea within the 16-lane group
#pragma unroll
        for (int off = 1; off < 16; off <<= 1) {
            zl += __shfl_xor(zl, off);
            seal += __shfl_xor(seal, off);
        }
        int d = end - start;
        float loop_sc = seal / (float)max(d, 1);
        float aself = leaky(ash[ic] + adi + loop_sc);
        float pself = __expf(aself);
        float z = zl + pself;

        uint2 hvs = *(const uint2*)(Hb + (((unsigned int)ic << 7) + fb));
        __half2 s01 = *(__half2*)&hvs.x;
        __half2 s23 = *(__half2*)&hvs.y;
        acc0 = fmaf(pself, __half2float(s01.x), acc0);
        acc1 = fmaf(pself, __half2float(s01.y), acc1);
        acc2 = fmaf(pself, __half2float(s23.x), acc2);
        acc3 = fmaf(pself, __half2float(s23.y), acc3);

        float4 bv = *(const float4*)(bias + fl * 4);
        float4 o;
        o.x = fmaxf(acc0 / z + bv.x, 0.f);
        o.y = fmaxf(acc1 / z + bv.y, 0.f);
        o.z = fmaxf(acc2 / z + bv.z, 0.f);
        o.w = fmaxf(acc3 / z + bv.w, 0.f);

        if (LAYER == 0) {
            *(float4*)(outp + (size_t)i * 64 + fl * 4) = o;
        } else {
            // fused classifier MLP: relu(o@Wc1+bc1)@Wc2+bc2 -> logits (n x 32)
            float* wc1s = mlpbuf;
            float* wc2s = mlpbuf + 2048;
            float* bcs = mlpbuf + 3072;
            float* o_row = mlpbuf + 3136 + (wave * 4 + gr) * 64;
            float* t1row = mlpbuf + 3136 + 1024 + (wave * 4 + gr) * 32;
            *(float4*)(o_row + fl * 4) = o;
            float s0 = bcs[fl * 2], s1 = bcs[fl * 2 + 1];
#pragma unroll 8
            for (int k = 0; k < 64; ++k) {
                float ov = o_row[k];
                s0 = fmaf(ov, wc1s[k * 32 + fl * 2], s0);
                s1 = fmaf(ov, wc1s[k * 32 + fl * 2 + 1], s1);
            }
            s0 = fmaxf(s0, 0.f);
            s1 = fmaxf(s1, 0.f);
            t1row[fl * 2] = s0;
            t1row[fl * 2 + 1] = s1;
            float l0 = bcs[32 + fl * 2], l1 = bcs[32 + fl * 2 + 1];
#pragma unroll 8
            for (int k = 0; k < 32; ++k) {
                float tv = t1row[k];
                l0 = fmaf(tv, wc2s[k * 32 + fl * 2], l0);
                l1 = fmaf(tv, wc2s[k * 32 + fl * 2 + 1], l1);
            }
            *(float2*)(outp + (size_t)i * 32 + fl * 2) = make_float2(l0, l1);
        }
    }
}

extern "C" void kernel_launch(void* const* d_in, const int* in_sizes, int n_in,
                              void* d_out, int out_size, void* d_ws, size_t ws_size,
                              hipStream_t stream) {
    const float* x    = (const float*)d_in[0];
    const int*   ei   = (const int*)d_in[1];
    const float* eatt = (const float*)d_in[2];
    const float* W1   = (const float*)d_in[3];
    const float* as1  = (const float*)d_in[4];
    const float* ad1  = (const float*)d_in[5];
    const float* We1  = (const float*)d_in[6];
    const float* ae1  = (const float*)d_in[7];
    const float* b1   = (const float*)d_in[8];
    const float* W2   = (const float*)d_in[9];
    const float* as2  = (const float*)d_in[10];
    const float* ad2  = (const float*)d_in[11];
    const float* We2  = (const float*)d_in[12];
    const float* ae2  = (const float*)d_in[13];
    const float* b2   = (const float*)d_in[14];
    const float* Wc1  = (const float*)d_in[15];
    const float* bc1  = (const float*)d_in[16];
    const float* Wc2  = (const float*)d_in[17];
    const float* bc2  = (const float*)d_in[18];

    int n = in_sizes[0] / 128;
    int E = in_sizes[1] / 2;
    const int* src = ei;
    const int* dst = ei + E;
    int nblk = (E + EPB - 1) / EPB;  // must be <= 1024 (E <= 2.09M)

    // workspace carve (256B aligned)
    char* w = (char*)d_ws;
    auto alloc = [&](size_t bytes) { void* p = (void*)w; w += (bytes + 255) & ~(size_t)255; return p; };
    int* rowptr   = (int*)alloc((size_t)(n + 1) * 4);
    int* counts   = (int*)alloc((size_t)nblk * NBUK * 4);
    int* offsets  = (int*)alloc((size_t)nblk * NBUK * 4);
    int* btot     = (int*)alloc((size_t)NBUK * 4);
    int* bbase    = (int*)alloc((size_t)NBUK * 4);
    unsigned int* meta_pay = (unsigned int*)alloc((size_t)E * 4);
    uint2* recs   = (uint2*)alloc((size_t)E * 8);
    __half* hbuf16 = (__half*)alloc((size_t)n * 64 * 2);
    float* obuf   = (float*)alloc((size_t)n * 64 * 4);
    float* ash    = (float*)alloc((size_t)n * 4);
    float* adh    = (float*)alloc((size_t)n * 4);
    __half* Wt1   = (__half*)alloc(64 * 128 * 2);
    __half* Wt2   = (__half*)alloc(64 * 64 * 2);
    // bucketed edge array aliases obuf (dead until gat_aggregate<0> writes obuf)
    uint2* bucketed = (uint2*)obuf;

    // ---- weight prep (independent of everything else) ----
    prep_w<<<48, 256, 0, stream>>>(W1, W2, Wt1, Wt2);

    // ---- CSR build: no global returning atomics anywhere ----
    count_pack<<<nblk, 256, 0, stream>>>(dst, eatt, We1, ae1, We2, ae2, meta_pay, counts, E);
    scan_cols<<<NBUK, 1024, 0, stream>>>(counts, offsets, btot, nblk);
    scan_buckets<<<1, NBUK, 0, stream>>>(btot, bbase, rowptr, E, n);
    scatter_buckets<<<nblk, 256, 0, stream>>>(dst, src, meta_pay, offsets, bbase, bucketed, E);
    csr_build<<<NBUK, 256, 0, stream>>>(bucketed, bbase, btot, rowptr, recs, n);

    // layer 1
    gemm_node_mfma<128><<<(n + 63) / 64, 256, 0, stream>>>(x, Wt1, as1, ad1, hbuf16, ash, adh, n);
    gat_aggregate<0><<<(n + 15) / 16, 256, 0, stream>>>(hbuf16, ash, adh, rowptr, recs, b1,
                                                        nullptr, nullptr, nullptr, nullptr, obuf, n);
    // layer 2 (+ fused classifier MLP)
    gemm_node_mfma<64><<<(n + 63) / 64, 256, 0, stream>>>(obuf, Wt2, as2, ad2, hbuf16, ash, adh, n);
    gat_aggregate<1><<<(n + 15) / 16, 256, 0, stream>>>(hbuf16, ash, adh, rowptr, recs, b2,
                                                        Wc1, bc1, Wc2, bc2, (float*)d_out, n);
}

// Round 9
// 430.206 us; speedup vs baseline: 1.2350x; 1.0081x over previous
//
#include <hip/hip_runtime.h>
#include <hip/hip_bf16.h>
#include <hip/hip_fp16.h>

#define NEG_SLOPE 0.2f
// CSR build geometry: 512 dst-buckets of 256 nodes (assumes n <= 131072),
// 2048 edges per counting block (assumes E <= 2048*1024 = 2.09M).
#define EPB 2048
#define NBUK 512

typedef _Float16 f16x8 __attribute__((ext_vector_type(8)));
typedef float f32x4 __attribute__((ext_vector_type(4)));

__device__ __forceinline__ float leaky(float a) { return a > 0.f ? a : NEG_SLOPE * a; }

// ---------------- K0: W transpose + f16 convert (Wt[c][k] = W[k][c]) ----------------
__global__ __launch_bounds__(256) void prep_w(const float* __restrict__ W1,
                                              const float* __restrict__ W2,
                                              __half* __restrict__ Wt1,
                                              __half* __restrict__ Wt2) {
    int t = threadIdx.x + blockIdx.x * 256;
    if (t < 8192) {
        int k = t >> 6, c = t & 63;
        Wt1[c * 128 + k] = __float2half_rn(W1[t]);
    } else if (t < 12288) {
        int i = t - 8192;
        int k = i >> 6, c = i & 63;
        Wt2[c * 64 + k] = __float2half_rn(W2[i]);
    }
}

// ---------------- K1: per-block bucket histogram + edge payload (f16|f16) ----------------
__global__ __launch_bounds__(256) void count_pack(
    const int* __restrict__ dst, const float* __restrict__ eattr,
    const float* __restrict__ We1, const float* __restrict__ ae1,
    const float* __restrict__ We2, const float* __restrict__ ae2,
    unsigned int* __restrict__ meta_pay, int* __restrict__ counts, int E) {
    __shared__ float wvs[32];
    __shared__ int hist[NBUK];
    int tid = threadIdx.x, i = blockIdx.x;
    if (tid < 32) {
        const float* Wp = (tid < 16) ? We1 : We2;
        const float* ap = (tid < 16) ? ae1 : ae2;
        int f = tid & 15;
        float s = 0.f;
        for (int k = 0; k < 64; ++k) s += Wp[f * 64 + k] * ap[k];
        wvs[tid] = s;
    }
    for (int t = tid; t < NBUK; t += 256) hist[t] = 0;
    __syncthreads();
    int e0 = i * EPB, e1 = min(E, e0 + EPB);
    for (int e = e0 + tid; e < e1; e += 256) {
        int d = dst[e];
        atomicAdd(&hist[d >> 8], 1);
        const float4* ep = (const float4*)(eattr + (size_t)e * 16);
        float4 q0 = ep[0], q1 = ep[1], q2 = ep[2], q3 = ep[3];
        float a[16] = {q0.x, q0.y, q0.z, q0.w, q1.x, q1.y, q1.z, q1.w,
                       q2.x, q2.y, q2.z, q2.w, q3.x, q3.y, q3.z, q3.w};
        float s1 = 0.f, s2 = 0.f;
#pragma unroll
        for (int f = 0; f < 16; ++f) { s1 += a[f] * wvs[f]; s2 += a[f] * wvs[16 + f]; }
        unsigned int p1 = (unsigned int)__half_as_ushort(__float2half_rn(s1));
        unsigned int p2 = (unsigned int)__half_as_ushort(__float2half_rn(s2));
        meta_pay[e] = p1 | (p2 << 16);
    }
    __syncthreads();
    for (int t = tid; t < NBUK; t += 256) counts[(size_t)i * NBUK + t] = hist[t];
}

// ---------------- K2a: per-bucket exclusive scan over blocks ----------------
__global__ __launch_bounds__(1024) void scan_cols(const int* __restrict__ counts,
                                                  int* __restrict__ offsets,
                                                  int* __restrict__ btot, int nblk) {
    __shared__ int sh[1024];
    int b = blockIdx.x, t = threadIdx.x;
    int v = (t < nblk) ? counts[(size_t)t * NBUK + b] : 0;
    sh[t] = v;
    __syncthreads();
    for (int off = 1; off < 1024; off <<= 1) {
        int u = (t >= off) ? sh[t - off] : 0;
        __syncthreads();
        sh[t] += u;
        __syncthreads();
    }
    if (t < nblk) offsets[(size_t)t * NBUK + b] = sh[t] - v;
    if (t == 1023) btot[b] = sh[1023];
}

// ---------------- K2b: exclusive scan of 512 bucket totals -> bucket bases ----------------
__global__ void scan_buckets(const int* __restrict__ btot, int* __restrict__ bbase,
                             int* __restrict__ rowptr, int E, int n) {
    __shared__ int sh[NBUK];
    int t = threadIdx.x;
    int v = btot[t];
    sh[t] = v;
    __syncthreads();
    for (int off = 1; off < NBUK; off <<= 1) {
        int u = (t >= off) ? sh[t - off] : 0;
        __syncthreads();
        sh[t] += u;
        __syncthreads();
    }
    bbase[t] = sh[t] - v;
    if (t == 0) rowptr[n] = E;
}

// ---------------- K3: scatter edges into dst-bucketed array (LDS cursors only) ----------------
__global__ __launch_bounds__(256) void scatter_buckets(
    const int* __restrict__ dst, const int* __restrict__ src,
    const unsigned int* __restrict__ meta_pay, const int* __restrict__ offsets,
    const int* __restrict__ bbase, uint2* __restrict__ bucketed, int E) {
    __shared__ int cur[NBUK];
    int i = blockIdx.x, tid = threadIdx.x;
    for (int t = tid; t < NBUK; t += 256) cur[t] = bbase[t] + offsets[(size_t)i * NBUK + t];
    __syncthreads();
    int e0 = i * EPB, e1 = min(E, e0 + EPB);
    for (int e = e0 + tid; e < e1; e += 256) {
        int d = dst[e];
        int slot = atomicAdd(&cur[d >> 8], 1);
        bucketed[slot] = make_uint2((unsigned int)src[e] | ((unsigned int)(d & 255) << 24),
                                    meta_pay[e]);
    }
}

// ---------------- K4: per-bucket degree count + LDS scan -> rowptr + final CSR recs ----------------
__global__ __launch_bounds__(256) void csr_build(const uint2* __restrict__ bucketed,
                                                 const int* __restrict__ bbase,
                                                 const int* __restrict__ btot,
                                                 int* __restrict__ rowptr,
                                                 uint2* __restrict__ recs, int n) {
    __shared__ int deg[256], sc[256], cur[256];
    int b = blockIdx.x, tid = threadIdx.x;
    int base = bbase[b], cnt = btot[b];
    deg[tid] = 0;
    __syncthreads();
    for (int k = tid; k < cnt; k += 256) {
        uint2 r = bucketed[base + k];
        atomicAdd(&deg[r.x >> 24], 1);
    }
    __syncthreads();
    int dv = deg[tid];
    sc[tid] = dv;
    __syncthreads();
    for (int off = 1; off < 256; off <<= 1) {
        int u = (tid >= off) ? sc[tid - off] : 0;
        __syncthreads();
        sc[tid] += u;
        __syncthreads();
    }
    int excl = sc[tid] - dv;
    int d = b * 256 + tid;
    if (d < n) rowptr[d] = base + excl;
    cur[tid] = base + excl;
    __syncthreads();
    for (int k = tid; k < cnt; k += 256) {
        uint2 r = bucketed[base + k];
        int dl = (int)(r.x >> 24);
        int pos = atomicAdd(&cur[dl], 1);
        recs[pos] = make_uint2(r.x & 0x00FFFFFFu, r.y);
    }
}

// ---------------- node GEMM via MFMA: h = X@W -> f16 rows + ash/adh ----------------
// LDS-free, barrier-free. Wave computes 16 nodes x 64 features (m89-verified D layout).
template <int K>
__global__ __launch_bounds__(256) void gemm_node_mfma(
    const float* __restrict__ X, const __half* __restrict__ Wt,
    const float* __restrict__ a_s, const float* __restrict__ a_d,
    __half* __restrict__ Hout16, float* __restrict__ ash, float* __restrict__ adh, int n) {
    int tid = threadIdx.x;
    int wave = tid >> 6, lane = tid & 63;
    int g = lane >> 4, q15 = lane & 15;
    int node = blockIdx.x * 64 + wave * 16 + q15;
    int nodec = min(node, n - 1);
    const float* xrow = X + (size_t)nodec * K + g * 8;
    const _Float16* wbase = (const _Float16*)Wt + (size_t)q15 * K + g * 8;

    f32x4 acc[4];
#pragma unroll
    for (int t = 0; t < 4; ++t) acc[t] = (f32x4){0.f, 0.f, 0.f, 0.f};

#pragma unroll
    for (int kk = 0; kk < K / 32; ++kk) {
        float4 xa = *(const float4*)(xrow + kk * 32);
        float4 xc = *(const float4*)(xrow + kk * 32 + 4);
        f16x8 xb;
        xb[0] = (_Float16)xa.x; xb[1] = (_Float16)xa.y;
        xb[2] = (_Float16)xa.z; xb[3] = (_Float16)xa.w;
        xb[4] = (_Float16)xc.x; xb[5] = (_Float16)xc.y;
        xb[6] = (_Float16)xc.z; xb[7] = (_Float16)xc.w;
#pragma unroll
        for (int t = 0; t < 4; ++t) {
            f16x8 wa = *(const f16x8*)(wbase + t * 16 * K + kk * 32);
            acc[t] = __builtin_amdgcn_mfma_f32_16x16x32_f16(wa, xb, acc[t], 0, 0, 0);
        }
    }

    float ps = 0.f, pd = 0.f;
#pragma unroll
    for (int t = 0; t < 4; ++t)
#pragma unroll
        for (int r = 0; r < 4; ++r) {
            int f = t * 16 + g * 4 + r;
            ps = fmaf(acc[t][r], a_s[f], ps);
            pd = fmaf(acc[t][r], a_d[f], pd);
        }
    ps += __shfl_xor(ps, 16); pd += __shfl_xor(pd, 16);
    ps += __shfl_xor(ps, 32); pd += __shfl_xor(pd, 32);

    if (node < n) {
#pragma unroll
        for (int t = 0; t < 4; ++t) {
            union { _Float16 h[4]; uint2 u2; } pk;
#pragma unroll
            for (int r = 0; r < 4; ++r) pk.h[r] = (_Float16)acc[t][r];
            *(uint2*)(Hout16 + (size_t)node * 64 + t * 16 + g * 4) = pk.u2;
        }
        if (g == 0) { ash[node] = ps; adh[node] = pd; }
    }
}

// ---------------- GAT aggregation: 4 nodes/wave; LAYER==1 fuses the classifier MLP ----------------
// MLP LDS layout PADDED: o_row stride 68, t1row stride 36 -> the 4 groups of a wave land on
// distinct banks (nl*68 mod 32 = 4*nl), killing the round-8 4-way broadcast conflicts (1.6M).
#define OROW_STRIDE 68
#define T1_STRIDE 36
template <int LAYER>
__global__ __launch_bounds__(256) void gat_aggregate(
    const __half* __restrict__ Hf, const float* __restrict__ ash, const float* __restrict__ adh,
    const int* __restrict__ rowptr, const uint2* __restrict__ recs,
    const float* __restrict__ bias,
    const float* __restrict__ Wc1, const float* __restrict__ bc1,
    const float* __restrict__ Wc2, const float* __restrict__ bc2,
    float* __restrict__ outp, int n) {
    __shared__ uint2 ops[4][4 * 17];
    // LAYER==1: wc1s(2048) | wc2s(1024) | bc (64) | o rows (16*68) | t1 rows (16*36)
    __shared__ float mlpbuf[LAYER ? (2048 + 1024 + 64 + 16 * OROW_STRIDE + 16 * T1_STRIDE) : 1];

    if (LAYER == 1) {
        for (int t = threadIdx.x; t < 2048; t += 256) mlpbuf[t] = Wc1[t];
        for (int t = threadIdx.x; t < 1024; t += 256) mlpbuf[2048 + t] = Wc2[t];
        if (threadIdx.x < 32) mlpbuf[3072 + threadIdx.x] = bc1[threadIdx.x];
        else if (threadIdx.x < 64) mlpbuf[3072 + threadIdx.x] = bc2[threadIdx.x - 32];
        __syncthreads();
    }

    int wave = threadIdx.x >> 6;
    int lane = threadIdx.x & 63;
    int gr = lane >> 4;
    int fl = lane & 15;
    int i = blockIdx.x * 16 + wave * 4 + gr;
    bool valid = i < n;
    int ic = valid ? i : 0;
    int start = 0, end = 0;
    if (valid) { start = rowptr[i]; end = rowptr[i + 1]; }
    float adi = adh[ic];
    const char* Hb = (const char*)Hf;
    unsigned int fb = (unsigned int)(fl * 8);

    float acc0 = 0.f, acc1 = 0.f, acc2 = 0.f, acc3 = 0.f;
    float zl = 0.f, seal = 0.f;

    for (int c = start; c < end; c += 16) {
        int cnt = min(16, end - c);
        unsigned int o_l = 0;
        float p_l = 0.f;
        if (fl < cnt) {
            uint2 r = recs[c + fl];
            int s_l = (int)r.x;
            o_l = (unsigned int)s_l << 7;
            unsigned short u = (LAYER == 0) ? (unsigned short)(r.y & 0xffffu)
                                            : (unsigned short)(r.y >> 16);
            float e = __half2float(__ushort_as_half(u));
            float p = __expf(leaky(ash[s_l] + adi + e));
            p_l = p;
            zl += p;
            seal += e;
        }
        ops[wave][gr * 17 + fl] = make_uint2(o_l, __float_as_uint(p_l));
        // same-wave LDS dependency; lgkmcnt ordering, no barrier needed
        for (int k = 0; k < cnt; ++k) {
            uint2 op = ops[wave][gr * 17 + k];  // group-uniform -> LDS broadcast
            uint2 hv = *(const uint2*)(Hb + (op.x + fb));
            float p = __uint_as_float(op.y);
            __half2 h01 = *(__half2*)&hv.x;
            __half2 h23 = *(__half2*)&hv.y;
            acc0 = fmaf(p, __half2float(h01.x), acc0);
            acc1 = fmaf(p, __half2float(h01.y), acc1);
            acc2 = fmaf(p, __half2float(h23.x), acc2);
            acc3 = fmaf(p, __half2float(h23.y), acc3);
        }
    }

    if (valid) {
        // reduce z / sea within the 16-lane group
#pragma unroll
        for (int off = 1; off < 16; off <<= 1) {
            zl += __shfl_xor(zl, off);
            seal += __shfl_xor(seal, off);
        }
        int d = end - start;
        float loop_sc = seal / (float)max(d, 1);
        float aself = leaky(ash[ic] + adi + loop_sc);
        float pself = __expf(aself);
        float z = zl + pself;

        uint2 hvs = *(const uint2*)(Hb + (((unsigned int)ic << 7) + fb));
        __half2 s01 = *(__half2*)&hvs.x;
        __half2 s23 = *(__half2*)&hvs.y;
        acc0 = fmaf(pself, __half2float(s01.x), acc0);
        acc1 = fmaf(pself, __half2float(s01.y), acc1);
        acc2 = fmaf(pself, __half2float(s23.x), acc2);
        acc3 = fmaf(pself, __half2float(s23.y), acc3);

        float4 bv = *(const float4*)(bias + fl * 4);
        float4 o;
        o.x = fmaxf(acc0 / z + bv.x, 0.f);
        o.y = fmaxf(acc1 / z + bv.y, 0.f);
        o.z = fmaxf(acc2 / z + bv.z, 0.f);
        o.w = fmaxf(acc3 / z + bv.w, 0.f);

        if (LAYER == 0) {
            *(float4*)(outp + (size_t)i * 64 + fl * 4) = o;
        } else {
            // fused classifier MLP: relu(o@Wc1+bc1)@Wc2+bc2 -> logits (n x 32)
            int nl = wave * 4 + gr;
            float* wc1s = mlpbuf;
            float* wc2s = mlpbuf + 2048;
            float* bcs = mlpbuf + 3072;
            float* o_row = mlpbuf + 3136 + nl * OROW_STRIDE;
            float* t1row = mlpbuf + 3136 + 16 * OROW_STRIDE + nl * T1_STRIDE;
            *(float4*)(o_row + fl * 4) = o;
            float s0 = bcs[fl * 2], s1 = bcs[fl * 2 + 1];
#pragma unroll 8
            for (int k = 0; k < 64; ++k) {
                float ov = o_row[k];  // group-uniform broadcast, bank 4*nl (+k)
                float2 wp = *(const float2*)(wc1s + k * 32 + fl * 2);
                s0 = fmaf(ov, wp.x, s0);
                s1 = fmaf(ov, wp.y, s1);
            }
            s0 = fmaxf(s0, 0.f);
            s1 = fmaxf(s1, 0.f);
            t1row[fl * 2] = s0;
            t1row[fl * 2 + 1] = s1;
            float l0 = bcs[32 + fl * 2], l1 = bcs[32 + fl * 2 + 1];
#pragma unroll 8
            for (int k = 0; k < 32; ++k) {
                float tv = t1row[k];
                float2 wp = *(const float2*)(wc2s + k * 32 + fl * 2);
                l0 = fmaf(tv, wp.x, l0);
                l1 = fmaf(tv, wp.y, l1);
            }
            *(float2*)(outp + (size_t)i * 32 + fl * 2) = make_float2(l0, l1);
        }
    }
}

extern "C" void kernel_launch(void* const* d_in, const int* in_sizes, int n_in,
                              void* d_out, int out_size, void* d_ws, size_t ws_size,
                              hipStream_t stream) {
    const float* x    = (const float*)d_in[0];
    const int*   ei   = (const int*)d_in[1];
    const float* eatt = (const float*)d_in[2];
    const float* W1   = (const float*)d_in[3];
    const float* as1  = (const float*)d_in[4];
    const float* ad1  = (const float*)d_in[5];
    const float* We1  = (const float*)d_in[6];
    const float* ae1  = (const float*)d_in[7];
    const float* b1   = (const float*)d_in[8];
    const float* W2   = (const float*)d_in[9];
    const float* as2  = (const float*)d_in[10];
    const float* ad2  = (const float*)d_in[11];
    const float* We2  = (const float*)d_in[12];
    const float* ae2  = (const float*)d_in[13];
    const float* b2   = (const float*)d_in[14];
    const float* Wc1  = (const float*)d_in[15];
    const float* bc1  = (const float*)d_in[16];
    const float* Wc2  = (const float*)d_in[17];
    const float* bc2  = (const float*)d_in[18];

    int n = in_sizes[0] / 128;
    int E = in_sizes[1] / 2;
    const int* src = ei;
    const int* dst = ei + E;
    int nblk = (E + EPB - 1) / EPB;  // must be <= 1024 (E <= 2.09M)

    // workspace carve (256B aligned)
    char* w = (char*)d_ws;
    auto alloc = [&](size_t bytes) { void* p = (void*)w; w += (bytes + 255) & ~(size_t)255; return p; };
    int* rowptr   = (int*)alloc((size_t)(n + 1) * 4);
    int* counts   = (int*)alloc((size_t)nblk * NBUK * 4);
    int* offsets  = (int*)alloc((size_t)nblk * NBUK * 4);
    int* btot     = (int*)alloc((size_t)NBUK * 4);
    int* bbase    = (int*)alloc((size_t)NBUK * 4);
    unsigned int* meta_pay = (unsigned int*)alloc((size_t)E * 4);
    uint2* recs   = (uint2*)alloc((size_t)E * 8);
    __half* hbuf16 = (__half*)alloc((size_t)n * 64 * 2);
    float* obuf   = (float*)alloc((size_t)n * 64 * 4);
    float* ash    = (float*)alloc((size_t)n * 4);
    float* adh    = (float*)alloc((size_t)n * 4);
    __half* Wt1   = (__half*)alloc(64 * 128 * 2);
    __half* Wt2   = (__half*)alloc(64 * 64 * 2);
    // bucketed edge array aliases obuf (dead until gat_aggregate<0> writes obuf)
    uint2* bucketed = (uint2*)obuf;

    // ---- weight prep (independent of everything else) ----
    prep_w<<<48, 256, 0, stream>>>(W1, W2, Wt1, Wt2);

    // ---- CSR build: no global returning atomics anywhere ----
    count_pack<<<nblk, 256, 0, stream>>>(dst, eatt, We1, ae1, We2, ae2, meta_pay, counts, E);
    scan_cols<<<NBUK, 1024, 0, stream>>>(counts, offsets, btot, nblk);
    scan_buckets<<<1, NBUK, 0, stream>>>(btot, bbase, rowptr, E, n);
    scatter_buckets<<<nblk, 256, 0, stream>>>(dst, src, meta_pay, offsets, bbase, bucketed, E);
    csr_build<<<NBUK, 256, 0, stream>>>(bucketed, bbase, btot, rowptr, recs, n);

    // layer 1
    gemm_node_mfma<128><<<(n + 63) / 64, 256, 0, stream>>>(x, Wt1, as1, ad1, hbuf16, ash, adh, n);
    gat_aggregate<0><<<(n + 15) / 16, 256, 0, stream>>>(hbuf16, ash, adh, rowptr, recs, b1,
                                                        nullptr, nullptr, nullptr, nullptr, obuf, n);
    // layer 2 (+ fused classifier MLP)
    gemm_node_mfma<64><<<(n + 63) / 64, 256, 0, stream>>>(obuf, Wt2, as2, ad2, hbuf16, ash, adh, n);
    gat_aggregate<1><<<(n + 15) / 16, 256, 0, stream>>>(hbuf16, ash, adh, rowptr, recs, b2,
                                                        Wc1, bc1, Wc2, bc2, (float*)d_out, n);
}